// Round 1
// baseline (11134.681 us; speedup 1.0000x reference)
//
#include <hip/hip_runtime.h>
#include <cstddef>
#include <cstdint>

// ---------------- workspace layout (float offsets) ----------------
static const size_t OFF_KEYT   = 0;          // 20*32*1024   = 655360
static const size_t OFF_VALTT  = 655360;     // 20*1024*128  = 2621440 (transposed [n][q][v])
static const size_t OFF_KQ     = 3276800;    // 2*32*1024    = 65536
static const size_t OFF_VQT    = 3342336;    // 2*1024*128   = 262144 (transposed [b][q][v])
static const size_t OFF_MEANF  = 3604480;    // 512
static const size_t OFF_FR     = 3604992;    // 2*256*1024   = 524288
static const size_t OFF_FPART  = 4129280;    // 4*2*256*1024 = 2097152
static const size_t OFF_FSMALL = 6226432;    // 2*256*1024   = 524288
static const size_t OFF_FBIG   = 6750720;    // 2*256*16384  = 8388608
static const size_t OFF_MU     = 15139328;   // 256
static const size_t OFF_VAR    = 15139584;   // 256
static const size_t OFF_WCAT   = 15139840;   // 256*512     = 131072
static const size_t OFF_BIAS2  = 15270912;   // 256
static const size_t WS_FLOATS  = 15271168;   // ~61.1 MB

// ---------------- 3x3 SAME conv on 32x32 inputs, dual output sets ----------------
// grid: (N, (OCK+OCV)/8, 4 spatial 16x16 tiles), block 256
__global__ __launch_bounds__(256) void conv3x3_dual(
    const float* __restrict__ in,  // [N][256][32][32]
    const float* __restrict__ wk, const float* __restrict__ bk, int OCK,
    float* __restrict__ outk,      // [N][OCK][1024]   (normal layout)
    const float* __restrict__ wv, const float* __restrict__ bv, int OCV,
    float* __restrict__ outvT)     // [N][1024][OCV]   (transposed layout)
{
    const int tid = threadIdx.x;
    const int n   = blockIdx.x;
    const int g   = blockIdx.y;
    const int ty0 = (blockIdx.z >> 1) << 4;
    const int tx0 = (blockIdx.z & 1) << 4;
    const int KG  = OCK >> 3;
    const bool iskey = (g < KG);
    const int oc0 = (iskey ? g : (g - KG)) << 3;
    const float* __restrict__ w    = iskey ? wk : wv;
    const float* __restrict__ bias = iskey ? bk : bv;

    __shared__ float s_in[18][18];
    __shared__ float s_w[8][9];

    const int px = tid & 15, py = tid >> 4;
    float acc[8];
#pragma unroll
    for (int o = 0; o < 8; ++o) acc[o] = 0.f;

    const float* inbase = in + (size_t)n * 256 * 1024;
    for (int ic = 0; ic < 256; ++ic) {
        for (int i = tid; i < 324; i += 256) {
            int ry = i / 18, rx = i - ry * 18;
            int iy = ty0 + ry - 1, ix = tx0 + rx - 1;
            float v = 0.f;
            if ((unsigned)iy < 32u && (unsigned)ix < 32u)
                v = inbase[(size_t)ic * 1024 + iy * 32 + ix];
            s_in[ry][rx] = v;
        }
        if (tid < 72) {
            int o = tid / 9, k = tid - o * 9;
            s_w[o][k] = w[((size_t)(oc0 + o) * 256 + ic) * 9 + k];
        }
        __syncthreads();
        float x00=s_in[py+0][px+0], x01=s_in[py+0][px+1], x02=s_in[py+0][px+2];
        float x10=s_in[py+1][px+0], x11=s_in[py+1][px+1], x12=s_in[py+1][px+2];
        float x20=s_in[py+2][px+0], x21=s_in[py+2][px+1], x22=s_in[py+2][px+2];
#pragma unroll
        for (int o = 0; o < 8; ++o) {
            acc[o] += x00*s_w[o][0] + x01*s_w[o][1] + x02*s_w[o][2]
                    + x10*s_w[o][3] + x11*s_w[o][4] + x12*s_w[o][5]
                    + x20*s_w[o][6] + x21*s_w[o][7] + x22*s_w[o][8];
        }
        __syncthreads();
    }
    const int p = (ty0 + py) * 32 + tx0 + px;
    if (iskey) {
#pragma unroll
        for (int o = 0; o < 8; ++o)
            outk[((size_t)n * OCK + oc0 + o) * 1024 + p] = acc[o] + bias[oc0 + o];
    } else {
        float ob[8];
#pragma unroll
        for (int o = 0; o < 8; ++o) ob[o] = acc[o] + bias[oc0 + o];
        float* dst = outvT + ((size_t)n * 1024 + p) * OCV + oc0;
        *(float4*)(dst)     = make_float4(ob[0], ob[1], ob[2], ob[3]);
        *(float4*)(dst + 4) = make_float4(ob[4], ob[5], ob[6], ob[7]);
    }
}

// ---------------- per (b,c) spatial mean ----------------
__global__ __launch_bounds__(256) void mean2d_kernel(
    const float* __restrict__ f, float* __restrict__ mean, int HW)
{
    const int bc = blockIdx.x;
    const float* src = f + (size_t)bc * HW;
    float s = 0.f;
    for (int i = threadIdx.x; i < HW; i += 256) s += src[i];
#pragma unroll
    for (int off = 32; off; off >>= 1) s += __shfl_xor(s, off);
    __shared__ float red[4];
    if ((threadIdx.x & 63) == 0) red[threadIdx.x >> 6] = s;
    __syncthreads();
    if (threadIdx.x == 0)
        mean[bc] = (red[0] + red[1] + red[2] + red[3]) / (float)HW;
}

// ---------------- align-corners bilinear resize (optional per-(b,c) mean subtract) ----------------
__global__ __launch_bounds__(256) void resize_kernel(
    const float* __restrict__ in, float* __restrict__ out,
    const float* __restrict__ mean, int ih, int iw, int oh, int ow, int total)
{
    int idx = blockIdx.x * 256 + threadIdx.x;
    if (idx >= total) return;
    int x  = idx % ow;
    int y  = (idx / ow) % oh;
    int bc = idx / (ow * oh);
    float fy = (float)y * (float)(ih - 1) / (float)(oh - 1);
    float fx = (float)x * (float)(iw - 1) / (float)(ow - 1);
    int y0 = (int)fy; int y1 = min(y0 + 1, ih - 1); float wy = fy - (float)y0;
    int x0 = (int)fx; int x1 = min(x0 + 1, iw - 1); float wx = fx - (float)x0;
    const float* p = in + (size_t)bc * ih * iw;
    float a = p[y0 * iw + x0], b = p[y1 * iw + x0];
    float c = p[y0 * iw + x1], d = p[y1 * iw + x1];
    float c0 = a + (b - a) * wy;
    float c1 = c + (d - c) * wy;
    float v  = c0 + (c1 - c0) * wx;
    if (mean) v -= mean[bc];
    out[idx] = v;
}

// ---------------- fused relation attention (flash-style over q) ----------------
// p[b,n,q,t] = softmax_q( sum_c kq[b,c,q]*key_t[n,c,t] )
// out[b, 0:128, t]   = sum_{n,q} vq[b,:,q]    * p     (V rows 0..127)
// out[b, 128:256, t] = sum_{n,q} val_t[n,:,q] * p     (V rows 128..255)
// grid: (64 t-tiles, 2 b, 4 n-groups of 5), block 256
__global__ __launch_bounds__(256) void flash_kernel(
    const float* __restrict__ key_t,   // [20][32][1024]
    const float* __restrict__ kq,      // [2][32][1024]
    const float* __restrict__ val_tT,  // [20][1024][128]
    const float* __restrict__ vqT,     // [2][1024][128]
    float* __restrict__ fin_part)      // [4][2][256][1024]
{
    const int tid = threadIdx.x;
    const int t0  = blockIdx.x * 16;
    const int b   = blockIdx.y;
    const int ng  = blockIdx.z;

    __shared__ float s_kt[32][16];
    __shared__ float s_kq[32][32];
    __shared__ float s_v[32][260];    // [q][v], padded
    __shared__ float s_p[16][33];     // [t][q], padded
    __shared__ float s_m[16], s_l[16], s_scale[16];
    __shared__ float s_o[16][260];

    const int vg    = tid & 15;
    const int tg    = (tid >> 4) & 3;
    const int qg    = tid >> 6;
    const int qlane = tid & 31;

    float fin[4][16];
#pragma unroll
    for (int i = 0; i < 4; ++i)
#pragma unroll
        for (int j = 0; j < 16; ++j) fin[i][j] = 0.f;

    for (int n = ng * 5; n < ng * 5 + 5; ++n) {
        for (int i = tid; i < 512; i += 256) {
            int c = i >> 4, t = i & 15;
            s_kt[c][t] = key_t[((size_t)n * 32 + c) * 1024 + t0 + t];
        }
        if (tid < 16) { s_m[tid] = -3.0e38f; s_l[tid] = 0.f; }
        float acc[4][16];
#pragma unroll
        for (int i = 0; i < 4; ++i)
#pragma unroll
            for (int j = 0; j < 16; ++j) acc[i][j] = 0.f;
        __syncthreads();

        for (int q0 = 0; q0 < 1024; q0 += 32) {
            for (int i = tid; i < 1024; i += 256) {
                int c = i >> 5, q = i & 31;
                s_kq[c][q] = kq[((size_t)b * 32 + c) * 1024 + q0 + q];
            }
            {
                int q = tid >> 3, seg = tid & 7;
                const float* src = (seg < 4)
                    ? (vqT    + ((size_t)b * 1024 + q0 + q) * 128 + seg * 32)
                    : (val_tT + ((size_t)n * 1024 + q0 + q) * 128 + (seg - 4) * 32);
                const float4* s4 = (const float4*)src;
                float4* dst = (float4*)&s_v[q][seg * 32];
#pragma unroll
                for (int k = 0; k < 8; ++k) {
                    int kk = (k + seg) & 7;   // rotate to spread LDS write banks
                    dst[kk] = s4[kk];
                }
            }
            __syncthreads();

            // S + online softmax stats (2 iterations cover 16 t)
#pragma unroll
            for (int it = 0; it < 2; ++it) {
                int tl = (tid >> 5) + (it << 3);
                float s = 0.f;
#pragma unroll
                for (int c = 0; c < 32; ++c)
                    s += s_kq[c][qlane] * s_kt[c][tl];
                float mx = s;
#pragma unroll
                for (int off = 16; off; off >>= 1)
                    mx = fmaxf(mx, __shfl_xor(mx, off));
                float m_old = s_m[tl];
                float m_new = fmaxf(m_old, mx);
                float pv = __expf(s - m_new);
                float psum = pv;
#pragma unroll
                for (int off = 16; off; off >>= 1)
                    psum += __shfl_xor(psum, off);
                if (qlane == 0) {
                    s_scale[tl] = __expf(m_old - m_new);
                    s_m[tl] = m_new;
                    s_l[tl] = s_l[tl] * s_scale[tl] + psum;
                }
                s_p[tl][qlane] = pv;
            }
            __syncthreads();

            // PV: thread owns 4 t x 16 v over its 8-q subset
            float sc4[4];
#pragma unroll
            for (int i = 0; i < 4; ++i) sc4[i] = s_scale[tg * 4 + i];
#pragma unroll
            for (int i = 0; i < 4; ++i)
#pragma unroll
                for (int j = 0; j < 16; ++j) acc[i][j] *= sc4[i];
#pragma unroll
            for (int jj = 0; jj < 8; ++jj) {
                int q = (qg << 3) + jj;
                float p0 = s_p[tg * 4 + 0][q];
                float p1 = s_p[tg * 4 + 1][q];
                float p2 = s_p[tg * 4 + 2][q];
                float p3 = s_p[tg * 4 + 3][q];
                const float4* vrow = (const float4*)&s_v[q][vg << 4];
#pragma unroll
                for (int k4 = 0; k4 < 4; ++k4) {
                    float4 v4 = vrow[k4];
                    int j = k4 << 2;
                    acc[0][j+0] += p0 * v4.x; acc[0][j+1] += p0 * v4.y;
                    acc[0][j+2] += p0 * v4.z; acc[0][j+3] += p0 * v4.w;
                    acc[1][j+0] += p1 * v4.x; acc[1][j+1] += p1 * v4.y;
                    acc[1][j+2] += p1 * v4.z; acc[1][j+3] += p1 * v4.w;
                    acc[2][j+0] += p2 * v4.x; acc[2][j+1] += p2 * v4.y;
                    acc[2][j+2] += p2 * v4.z; acc[2][j+3] += p2 * v4.w;
                    acc[3][j+0] += p3 * v4.x; acc[3][j+1] += p3 * v4.y;
                    acc[3][j+2] += p3 * v4.z; acc[3][j+3] += p3 * v4.w;
                }
            }
            __syncthreads();
        }
        // finalize this n: divide by softmax denom and accumulate
        float linv[4];
#pragma unroll
        for (int i = 0; i < 4; ++i) linv[i] = 1.f / s_l[tg * 4 + i];
#pragma unroll
        for (int i = 0; i < 4; ++i)
#pragma unroll
            for (int j = 0; j < 16; ++j) fin[i][j] += acc[i][j] * linv[i];
        __syncthreads();
    }

    // reduce the 4 q-subsets through LDS, then write out
    for (int i = tid; i < 16 * 260; i += 256) ((float*)s_o)[i] = 0.f;
    __syncthreads();
    for (int pass = 0; pass < 4; ++pass) {
        if (qg == pass) {
#pragma unroll
            for (int i = 0; i < 4; ++i)
#pragma unroll
                for (int j = 0; j < 16; ++j)
                    s_o[tg * 4 + i][(vg << 4) + j] += fin[i][j];
        }
        __syncthreads();
    }
    float* outp = fin_part + ((size_t)ng * 2 + b) * 256 * 1024;
    for (int i = tid; i < 4096; i += 256) {
        int t = i & 15, v = i >> 4;
        outp[(size_t)v * 1024 + t0 + t] = s_o[t][v];
    }
}

// ---------------- sum 4 n-group slabs ----------------
__global__ __launch_bounds__(256) void reduce4_kernel(
    const float* __restrict__ part, float* __restrict__ out)
{
    const int N = 524288;
    int idx = blockIdx.x * 256 + threadIdx.x;
    out[idx] = part[idx] + part[idx + N] + part[idx + 2 * N] + part[idx + 3 * N];
}

// ---------------- BN stats over (b, spatial) per channel ----------------
__global__ __launch_bounds__(256) void bnstats_kernel(
    const float* __restrict__ fin, float* __restrict__ mu, float* __restrict__ var, int HW)
{
    const int c = blockIdx.x;
    float s = 0.f, s2 = 0.f;
    for (int b = 0; b < 2; ++b) {
        const float* p = fin + ((size_t)b * 256 + c) * HW;
        for (int i = threadIdx.x; i < HW; i += 256) {
            float v = p[i]; s += v; s2 += v * v;
        }
    }
#pragma unroll
    for (int off = 32; off; off >>= 1) {
        s  += __shfl_xor(s, off);
        s2 += __shfl_xor(s2, off);
    }
    __shared__ float r1[4], r2[4];
    if ((threadIdx.x & 63) == 0) { r1[threadIdx.x >> 6] = s; r2[threadIdx.x >> 6] = s2; }
    __syncthreads();
    if (threadIdx.x == 0) {
        float cnt = 2.f * (float)HW;
        float m = (r1[0] + r1[1] + r1[2] + r1[3]) / cnt;
        float q = (r2[0] + r2[1] + r2[2] + r2[3]) / cnt;
        mu[c] = m; var[c] = q - m * m;
    }
}

// ---------------- fold BN into comb weights ----------------
__global__ __launch_bounds__(256) void prep_kernel(
    const float* __restrict__ comb_w, const float* __restrict__ comb_b,
    const float* __restrict__ gamma, const float* __restrict__ beta,
    const float* __restrict__ mu, const float* __restrict__ var,
    float* __restrict__ Wcat, float* __restrict__ bias2)
{
    const int oc = blockIdx.x;
    const int ic = threadIdx.x;
    float a  = gamma[ic] * rsqrtf(var[ic] + 1e-5f);
    float bb = beta[ic] - mu[ic] * a;
    float w1 = comb_w[(size_t)oc * 512 + ic];
    float w2 = comb_w[(size_t)oc * 512 + 256 + ic];
    Wcat[(size_t)oc * 512 + ic]       = w1;
    Wcat[(size_t)oc * 512 + 256 + ic] = w2 * a;
    float s = w2 * bb;
#pragma unroll
    for (int off = 32; off; off >>= 1) s += __shfl_xor(s, off);
    __shared__ float red[4];
    if ((threadIdx.x & 63) == 0) red[threadIdx.x >> 6] = s;
    __syncthreads();
    if (threadIdx.x == 0)
        bias2[oc] = comb_b[oc] + red[0] + red[1] + red[2] + red[3];
}

// ---------------- comb 1x1 conv as GEMM: out = Wcat @ [f; fin] + bias2 ----------------
// grid: (HW/64, 4, 2), block 256
__global__ __launch_bounds__(256) void comb_gemm_kernel(
    const float* __restrict__ f,    // [2][256][HW]
    const float* __restrict__ fin,  // [2][256][HW]
    const float* __restrict__ Wcat, // [256][512]
    const float* __restrict__ bias2,// [256]
    float* __restrict__ out, int HW)
{
    const int tid = threadIdx.x;
    const int p0  = blockIdx.x * 64;
    const int oc0 = blockIdx.y * 64;
    const int b   = blockIdx.z;
    __shared__ float s_w[64][16];
    __shared__ float s_x[16][64];
    const int tx = tid & 15, ty = tid >> 4;
    float acc[4][4];
#pragma unroll
    for (int i = 0; i < 4; ++i)
#pragma unroll
        for (int j = 0; j < 4; ++j) acc[i][j] = 0.f;

    for (int k0 = 0; k0 < 512; k0 += 16) {
        {
            int r = tid >> 2, c4 = (tid & 3) * 4;
            *(float4*)&s_w[r][c4] = *(const float4*)&Wcat[(size_t)(oc0 + r) * 512 + k0 + c4];
        }
        {
            int r = tid >> 4, c4 = (tid & 15) * 4;
            int k = k0 + r;
            const float* src = (k < 256)
                ? &f[((size_t)(b * 256 + k)) * HW + p0 + c4]
                : &fin[((size_t)(b * 256 + (k - 256))) * HW + p0 + c4];
            *(float4*)&s_x[r][c4] = *(const float4*)src;
        }
        __syncthreads();
#pragma unroll
        for (int kk = 0; kk < 16; ++kk) {
            float xv[4], wv[4];
#pragma unroll
            for (int j = 0; j < 4; ++j) xv[j] = s_x[kk][tx + 16 * j];
#pragma unroll
            for (int i = 0; i < 4; ++i) wv[i] = s_w[ty + 16 * i][kk];
#pragma unroll
            for (int i = 0; i < 4; ++i)
#pragma unroll
                for (int j = 0; j < 4; ++j) acc[i][j] += wv[i] * xv[j];
        }
        __syncthreads();
    }
#pragma unroll
    for (int i = 0; i < 4; ++i) {
        int oc = oc0 + ty + 16 * i;
        float bs = bias2[oc];
#pragma unroll
        for (int j = 0; j < 4; ++j)
            out[((size_t)(b * 256 + oc)) * HW + p0 + tx + 16 * j] = acc[i][j] + bs;
    }
}

// ---------------- host orchestration ----------------
extern "C" void kernel_launch(void* const* d_in, const int* in_sizes, int n_in,
                              void* d_out, int out_size, void* d_ws, size_t ws_size,
                              hipStream_t stream) {
    if (ws_size < WS_FLOATS * sizeof(float)) return;

    const float* feats[5];
    for (int i = 0; i < 5; ++i) feats[i] = (const float*)d_in[i];
    const float* attn     = (const float*)d_in[5];
    const float* key_t_w  = (const float*)d_in[6];
    const float* key_t_b  = (const float*)d_in[7];
    const float* val_t_w  = (const float*)d_in[8];
    const float* val_t_b  = (const float*)d_in[9];
    const float* key_q_w  = (const float*)d_in[10];
    const float* key_q_b  = (const float*)d_in[11];
    const float* val_q_w  = (const float*)d_in[12];
    const float* val_q_b  = (const float*)d_in[13];
    const float* bn_gamma = (const float*)d_in[14];
    const float* bn_beta  = (const float*)d_in[15];
    const float* comb_w   = (const float*)d_in[16];
    const float* comb_b   = (const float*)d_in[17];

    float* ws       = (float*)d_ws;
    float* key_t    = ws + OFF_KEYT;
    float* val_tT   = ws + OFF_VALTT;
    float* kq       = ws + OFF_KQ;
    float* vqT      = ws + OFF_VQT;
    float* mean_f   = ws + OFF_MEANF;
    float* fr       = ws + OFF_FR;
    float* fin_part = ws + OFF_FPART;
    float* fin_sm   = ws + OFF_FSMALL;
    float* fin_big  = ws + OFF_FBIG;
    float* mu       = ws + OFF_MU;
    float* var      = ws + OFF_VAR;
    float* Wcat     = ws + OFF_WCAT;
    float* bias2    = ws + OFF_BIAS2;

    // Stage A: key_t / val_t convs on attentions
    conv3x3_dual<<<dim3(20, 20, 4), 256, 0, stream>>>(
        attn, key_t_w, key_t_b, 32, key_t, val_t_w, val_t_b, 128, val_tT);

    static const int HH[5] = {128, 64, 32, 16, 8};
    size_t out_off = 0;
    for (int idx = 0; idx < 5; ++idx) {
        const int H = HH[idx], HW = H * H;
        const float* f = feats[idx];

        mean2d_kernel<<<512, 256, 0, stream>>>(f, mean_f, HW);

        resize_kernel<<<(2 * 256 * 1024) / 256, 256, 0, stream>>>(
            f, fr, mean_f, H, H, 32, 32, 2 * 256 * 1024);

        conv3x3_dual<<<dim3(2, 20, 4), 256, 0, stream>>>(
            fr,
            key_q_w + (size_t)idx * 32 * 256 * 9,  key_q_b + idx * 32,  32,  kq,
            val_q_w + (size_t)idx * 128 * 256 * 9, val_q_b + idx * 128, 128, vqT);

        flash_kernel<<<dim3(64, 2, 4), 256, 0, stream>>>(key_t, kq, val_tT, vqT, fin_part);

        reduce4_kernel<<<524288 / 256, 256, 0, stream>>>(fin_part, fin_sm);

        resize_kernel<<<(2 * 256 * HW + 255) / 256, 256, 0, stream>>>(
            fin_sm, fin_big, nullptr, 32, 32, H, H, 2 * 256 * HW);

        bnstats_kernel<<<256, 256, 0, stream>>>(fin_big, mu, var, HW);

        prep_kernel<<<256, 256, 0, stream>>>(
            comb_w, comb_b, bn_gamma + idx * 256, bn_beta + idx * 256, mu, var, Wcat, bias2);

        comb_gemm_kernel<<<dim3(HW / 64, 4, 2), 256, 0, stream>>>(
            f, fin_big, Wcat, bias2, (float*)d_out + out_off, HW);

        out_off += (size_t)2 * 256 * HW;
    }
}

// Round 2
// 3449.180 us; speedup vs baseline: 3.2282x; 3.2282x over previous
//
#include <hip/hip_runtime.h>
#include <cstddef>
#include <cstdint>

typedef __attribute__((ext_vector_type(8))) short bf16x8;
typedef __attribute__((ext_vector_type(16))) float f32x16;

// ---------------- workspace layout (byte offsets) ----------------
static const size_t B_KTHI  = 0;                       // 20*1024*32*2 = 1310720
static const size_t B_KTLO  = B_KTHI + 1310720;
static const size_t B_VTBF  = B_KTLO + 1310720;        // 20*128*1024*2 = 5242880
static const size_t B_KQHI  = B_VTBF + 5242880;        // 2*1024*32*2 = 131072
static const size_t B_KQLO  = B_KQHI + 131072;
static const size_t B_VQBF  = B_KQLO + 131072;         // 2*128*1024*2 = 524288
static const size_t B_MEAN  = B_VQBF + 524288;         // 512*4 = 2048
static const size_t B_FR    = B_MEAN + 2048;           // 2*256*1024*4 = 2097152
static const size_t B_FPART = B_FR + 2097152;          // 20*2*256*1024*4 = 41943040
static const size_t B_FBIG  = B_FPART;                 // alias: 2*256*16384*4 = 33554432 <= FPART
static const size_t B_FSM   = B_FPART + 41943040;      // 2*256*1024*4 = 2097152
static const size_t B_MU    = B_FSM + 2097152;         // 1024
static const size_t B_VAR   = B_MU + 1024;             // 1024
static const size_t B_WCAT  = B_VAR + 1024;            // 256*512*4 = 524288
static const size_t B_BIAS2 = B_WCAT + 524288;         // 1024
static const size_t WS_BYTES = B_BIAS2 + 1024;         // ~55.3 MB

// ---------------- bf16 helpers (RNE) ----------------
__device__ inline unsigned short f2bf(float x) {
    unsigned u = __float_as_uint(x);
    return (unsigned short)((u + 0x7fffu + ((u >> 16) & 1u)) >> 16);
}
__device__ inline void bf16split(float x, unsigned short& hi, unsigned short& lo) {
    unsigned u = __float_as_uint(x);
    unsigned hb = (u + 0x7fffu + ((u >> 16) & 1u)) >> 16;
    hi = (unsigned short)hb;
    float hf = __uint_as_float(hb << 16);
    float r = x - hf;
    unsigned ur = __float_as_uint(r);
    lo = (unsigned short)((ur + 0x7fffu + ((ur >> 16) & 1u)) >> 16);
}

// ---------------- 3x3 SAME conv on 32x32 inputs, bf16 outputs ----------------
// key path -> transposed [N][1024][32] hi/lo bf16; val path -> natural [N][128][1024] bf16
// grid: (N, 4+16 groups, 4 spatial 16x16 tiles), block 256
__global__ __launch_bounds__(256) void conv3x3_dual_bf16(
    const float* __restrict__ in,  // [N][256][32][32]
    const float* __restrict__ wk, const float* __restrict__ bk,
    unsigned short* __restrict__ k_hi, unsigned short* __restrict__ k_lo,
    const float* __restrict__ wv, const float* __restrict__ bv,
    unsigned short* __restrict__ v_bf)
{
    const int tid = threadIdx.x;
    const int n   = blockIdx.x;
    const int g   = blockIdx.y;
    const int ty0 = (blockIdx.z >> 1) << 4;
    const int tx0 = (blockIdx.z & 1) << 4;
    const bool iskey = (g < 4);
    const int oc0 = (iskey ? g : (g - 4)) << 3;
    const float* __restrict__ w    = iskey ? wk : wv;
    const float* __restrict__ bias = iskey ? bk : bv;

    __shared__ float s_in[18][18];
    __shared__ float s_w[8][9];

    const int px = tid & 15, py = tid >> 4;
    float acc[8];
#pragma unroll
    for (int o = 0; o < 8; ++o) acc[o] = 0.f;

    const float* inbase = in + (size_t)n * 256 * 1024;
    for (int ic = 0; ic < 256; ++ic) {
        for (int i = tid; i < 324; i += 256) {
            int ry = i / 18, rx = i - ry * 18;
            int iy = ty0 + ry - 1, ix = tx0 + rx - 1;
            float v = 0.f;
            if ((unsigned)iy < 32u && (unsigned)ix < 32u)
                v = inbase[(size_t)ic * 1024 + iy * 32 + ix];
            s_in[ry][rx] = v;
        }
        if (tid < 72) {
            int o = tid / 9, k = tid - o * 9;
            s_w[o][k] = w[((size_t)(oc0 + o) * 256 + ic) * 9 + k];
        }
        __syncthreads();
        float x00=s_in[py+0][px+0], x01=s_in[py+0][px+1], x02=s_in[py+0][px+2];
        float x10=s_in[py+1][px+0], x11=s_in[py+1][px+1], x12=s_in[py+1][px+2];
        float x20=s_in[py+2][px+0], x21=s_in[py+2][px+1], x22=s_in[py+2][px+2];
#pragma unroll
        for (int o = 0; o < 8; ++o) {
            acc[o] += x00*s_w[o][0] + x01*s_w[o][1] + x02*s_w[o][2]
                    + x10*s_w[o][3] + x11*s_w[o][4] + x12*s_w[o][5]
                    + x20*s_w[o][6] + x21*s_w[o][7] + x22*s_w[o][8];
        }
        __syncthreads();
    }
    const int p = (ty0 + py) * 32 + tx0 + px;
    if (iskey) {
        union { unsigned short s[8]; bf16x8 v; } h8, l8;
#pragma unroll
        for (int o = 0; o < 8; ++o)
            bf16split(acc[o] + bias[oc0 + o], h8.s[o], l8.s[o]);
        size_t base = ((size_t)n * 1024 + p) * 32 + oc0;
        *(bf16x8*)&k_hi[base] = h8.v;
        *(bf16x8*)&k_lo[base] = l8.v;
    } else {
#pragma unroll
        for (int o = 0; o < 8; ++o)
            v_bf[((size_t)n * 128 + oc0 + o) * 1024 + p] = f2bf(acc[o] + bias[oc0 + o]);
    }
}

// ---------------- per (b,c) spatial mean ----------------
__global__ __launch_bounds__(256) void mean2d_kernel(
    const float* __restrict__ f, float* __restrict__ mean, int HW)
{
    const int bc = blockIdx.x;
    const float* src = f + (size_t)bc * HW;
    float s = 0.f;
    for (int i = threadIdx.x; i < HW; i += 256) s += src[i];
#pragma unroll
    for (int off = 32; off; off >>= 1) s += __shfl_xor(s, off);
    __shared__ float red[4];
    if ((threadIdx.x & 63) == 0) red[threadIdx.x >> 6] = s;
    __syncthreads();
    if (threadIdx.x == 0)
        mean[bc] = (red[0] + red[1] + red[2] + red[3]) / (float)HW;
}

// ---------------- align-corners bilinear resize (optional mean subtract) ----------------
__global__ __launch_bounds__(256) void resize_kernel(
    const float* __restrict__ in, float* __restrict__ out,
    const float* __restrict__ mean, int ih, int iw, int oh, int ow, int total)
{
    int idx = blockIdx.x * 256 + threadIdx.x;
    if (idx >= total) return;
    int x  = idx % ow;
    int y  = (idx / ow) % oh;
    int bc = idx / (ow * oh);
    float fy = (float)y * (float)(ih - 1) / (float)(oh - 1);
    float fx = (float)x * (float)(iw - 1) / (float)(ow - 1);
    int y0 = (int)fy; int y1 = min(y0 + 1, ih - 1); float wy = fy - (float)y0;
    int x0 = (int)fx; int x1 = min(x0 + 1, iw - 1); float wx = fx - (float)x0;
    const float* p = in + (size_t)bc * ih * iw;
    float a = p[y0 * iw + x0], b = p[y1 * iw + x0];
    float c = p[y0 * iw + x1], d = p[y1 * iw + x1];
    float c0 = a + (b - a) * wy;
    float c1 = c + (d - c) * wy;
    float v  = c0 + (c1 - c0) * wx;
    if (mean) v -= mean[bc];
    out[idx] = v;
}

// ---------------- MFMA flash relation-attention ----------------
// S[q][t] = sum_c kq[b][c][q]*key_t[n][c][t]  (split-bf16: hi*hi + hi*lo + lo*hi)
// p = softmax_q(S); out[b][v][t] += sum_q V[v][q]*p, V = [vq[b]; val_t[n]]
// grid: (8 t-tiles of 128, 2 b, 20 n), block 256 = 4 waves (wave owns 32 t-cols)
__global__ __launch_bounds__(256, 1) void flash_mfma(
    const unsigned short* __restrict__ kt_hi, const unsigned short* __restrict__ kt_lo,
    const unsigned short* __restrict__ vt_bf,
    const unsigned short* __restrict__ kq_hi, const unsigned short* __restrict__ kq_lo,
    const unsigned short* __restrict__ vq_bf,
    float* __restrict__ fin_part)   // [20][2][256][1024]
{
    __shared__ unsigned short s_kt_h[128 * 40];
    __shared__ unsigned short s_kt_l[128 * 40];
    __shared__ unsigned short s_kq_h[32 * 40];
    __shared__ unsigned short s_kq_l[32 * 40];
    __shared__ unsigned short s_v[256 * 40];

    const int tid = threadIdx.x;
    const int t0  = blockIdx.x * 128;
    const int b   = blockIdx.y;
    const int n   = blockIdx.z;
    const int wave = tid >> 6;
    const int lane = tid & 63;
    const int l31  = lane & 31;
    const int lh   = lane >> 5;

    // stage key_t tile [128 t][32 c], hi & lo (rows padded to 40 ushorts)
    for (int c = tid; c < 512; c += 256) {
        int r = c >> 2, h = c & 3;
        size_t goff = ((size_t)(n * 1024 + t0 + r)) * 32 + h * 8;
        *(bf16x8*)&s_kt_h[r * 40 + h * 8] = *(const bf16x8*)&kt_hi[goff];
        *(bf16x8*)&s_kt_l[r * 40 + h * 8] = *(const bf16x8*)&kt_lo[goff];
    }
    __syncthreads();

    // hoist key_t B-fragments (constant per wave across the whole q-loop)
    bf16x8 btk_h[2], btk_l[2];
    const int trow = wave * 32 + l31;
#pragma unroll
    for (int kh = 0; kh < 2; ++kh) {
        btk_h[kh] = *(const bf16x8*)&s_kt_h[trow * 40 + kh * 16 + lh * 8];
        btk_l[kh] = *(const bf16x8*)&s_kt_l[trow * 40 + kh * 16 + lh * 8];
    }

    f32x16 acc[8] = {};
    float m = -3.0e38f, l = 0.f;

    for (int q0 = 0; q0 < 1024; q0 += 32) {
        // stage kq tile [32 q][32 c] hi/lo
        {
            int c = tid & 127;
            int r = c >> 2, h = c & 3;
            size_t goff = ((size_t)(b * 1024 + q0 + r)) * 32 + h * 8;
            const unsigned short* src = (tid < 128) ? kq_hi : kq_lo;
            unsigned short* dst = (tid < 128) ? s_kq_h : s_kq_l;
            *(bf16x8*)&dst[r * 40 + h * 8] = *(const bf16x8*)&src[goff];
        }
        // stage V tile [256 v][32 q]
        {
            const unsigned short* src = (tid < 128)
                ? &vq_bf[((size_t)(b * 128 + tid)) * 1024 + q0]
                : &vt_bf[((size_t)(n * 128 + (tid - 128))) * 1024 + q0];
            unsigned short* dst = &s_v[tid * 40];
#pragma unroll
            for (int c = 0; c < 4; ++c)
                *(bf16x8*)&dst[c * 8] = *(const bf16x8*)&src[c * 8];
        }
        __syncthreads();

        // S tile: [32 q][32 t] fp32 via split-bf16 MFMA
        f32x16 s = {};
#pragma unroll
        for (int kh = 0; kh < 2; ++kh) {
            bf16x8 ah = *(const bf16x8*)&s_kq_h[l31 * 40 + kh * 16 + lh * 8];
            bf16x8 al = *(const bf16x8*)&s_kq_l[l31 * 40 + kh * 16 + lh * 8];
            s = __builtin_amdgcn_mfma_f32_32x32x16_bf16(ah, btk_h[kh], s, 0, 0, 0);
            s = __builtin_amdgcn_mfma_f32_32x32x16_bf16(ah, btk_l[kh], s, 0, 0, 0);
            s = __builtin_amdgcn_mfma_f32_32x32x16_bf16(al, btk_h[kh], s, 0, 0, 0);
        }

        // online softmax over q — lane-local (lane holds one t-column, 16 q rows)
        float pmax = s[0];
#pragma unroll
        for (int r = 1; r < 16; ++r) pmax = fmaxf(pmax, s[r]);
        pmax = fmaxf(pmax, __shfl_xor(pmax, 32));
        if (!__all(pmax <= m + 8.f)) {   // defer-max (exact math, different norm const)
            float mnew = fmaxf(m, pmax);
            float sc = __expf(m - mnew);
            m = mnew;
            l *= sc;
#pragma unroll
            for (int vs = 0; vs < 8; ++vs) acc[vs] *= sc;
        }
        float pv[16]; float ps = 0.f;
#pragma unroll
        for (int r = 0; r < 16; ++r) { pv[r] = __expf(s[r] - m); ps += pv[r]; }
        ps += __shfl_xor(ps, 32);
        l += ps;

        // P -> B-operand frags: cvt_pk pairs + permlane32_swap (in-register)
        unsigned a0, a1, a2, a3, c0, c1, c2, c3;
        asm("v_cvt_pk_bf16_f32 %0, %1, %2" : "=v"(a0) : "v"(pv[0]),  "v"(pv[1]));
        asm("v_cvt_pk_bf16_f32 %0, %1, %2" : "=v"(a1) : "v"(pv[2]),  "v"(pv[3]));
        asm("v_cvt_pk_bf16_f32 %0, %1, %2" : "=v"(a2) : "v"(pv[4]),  "v"(pv[5]));
        asm("v_cvt_pk_bf16_f32 %0, %1, %2" : "=v"(a3) : "v"(pv[6]),  "v"(pv[7]));
        asm("v_cvt_pk_bf16_f32 %0, %1, %2" : "=v"(c0) : "v"(pv[8]),  "v"(pv[9]));
        asm("v_cvt_pk_bf16_f32 %0, %1, %2" : "=v"(c1) : "v"(pv[10]), "v"(pv[11]));
        asm("v_cvt_pk_bf16_f32 %0, %1, %2" : "=v"(c2) : "v"(pv[12]), "v"(pv[13]));
        asm("v_cvt_pk_bf16_f32 %0, %1, %2" : "=v"(c3) : "v"(pv[14]), "v"(pv[15]));
        asm("v_permlane32_swap_b32 %0, %1" : "+v"(a0), "+v"(a2));
        asm("v_permlane32_swap_b32 %0, %1" : "+v"(a1), "+v"(a3));
        asm("v_permlane32_swap_b32 %0, %1" : "+v"(c0), "+v"(c2));
        asm("v_permlane32_swap_b32 %0, %1" : "+v"(c1), "+v"(c3));
        union { unsigned u[4]; bf16x8 v; } f0, f1;
        f0.u[0] = a0; f0.u[1] = a1; f0.u[2] = a2; f0.u[3] = a3;
        f1.u[0] = c0; f1.u[1] = c1; f1.u[2] = c2; f1.u[3] = c3;

        // PV: acc[vs] += V[vs-tile] * P
#pragma unroll
        for (int vs = 0; vs < 8; ++vs) {
            const unsigned short* vr = &s_v[(vs * 32 + l31) * 40 + lh * 8];
            bf16x8 va0 = *(const bf16x8*)&vr[0];
            bf16x8 va1 = *(const bf16x8*)&vr[16];
            acc[vs] = __builtin_amdgcn_mfma_f32_32x32x16_bf16(va0, f0.v, acc[vs], 0, 0, 0);
            acc[vs] = __builtin_amdgcn_mfma_f32_32x32x16_bf16(va1, f1.v, acc[vs], 0, 0, 0);
        }
        __syncthreads();
    }

    // epilogue: divide by softmax denom, write per-n slab
    float linv = 1.f / l;
    float* outp = fin_part + ((size_t)(n * 2 + b)) * 256 * 1024;
    const int tg = t0 + wave * 32 + l31;
#pragma unroll
    for (int vs = 0; vs < 8; ++vs) {
#pragma unroll
        for (int r = 0; r < 16; ++r) {
            int v = vs * 32 + (r & 3) + 8 * (r >> 2) + 4 * lh;
            outp[(size_t)v * 1024 + tg] = acc[vs][r] * linv;
        }
    }
}

// ---------------- sum 20 n-slabs ----------------
__global__ __launch_bounds__(256) void reduce20_kernel(
    const float* __restrict__ part, float* __restrict__ out)
{
    size_t i = (size_t)blockIdx.x * 256 + threadIdx.x;
    float s = 0.f;
#pragma unroll
    for (int nn = 0; nn < 20; ++nn) s += part[(size_t)nn * 524288 + i];
    out[i] = s;
}

// ---------------- BN stats over (b, spatial) per channel ----------------
__global__ __launch_bounds__(256) void bnstats_kernel(
    const float* __restrict__ fin, float* __restrict__ mu, float* __restrict__ var, int HW)
{
    const int c = blockIdx.x;
    float s = 0.f, s2 = 0.f;
    for (int b = 0; b < 2; ++b) {
        const float* p = fin + ((size_t)b * 256 + c) * HW;
        for (int i = threadIdx.x; i < HW; i += 256) {
            float v = p[i]; s += v; s2 += v * v;
        }
    }
#pragma unroll
    for (int off = 32; off; off >>= 1) {
        s  += __shfl_xor(s, off);
        s2 += __shfl_xor(s2, off);
    }
    __shared__ float r1[4], r2[4];
    if ((threadIdx.x & 63) == 0) { r1[threadIdx.x >> 6] = s; r2[threadIdx.x >> 6] = s2; }
    __syncthreads();
    if (threadIdx.x == 0) {
        float cnt = 2.f * (float)HW;
        float m = (r1[0] + r1[1] + r1[2] + r1[3]) / cnt;
        float q = (r2[0] + r2[1] + r2[2] + r2[3]) / cnt;
        mu[c] = m; var[c] = q - m * m;
    }
}

// ---------------- fold BN into comb weights ----------------
__global__ __launch_bounds__(256) void prep_kernel(
    const float* __restrict__ comb_w, const float* __restrict__ comb_b,
    const float* __restrict__ gamma, const float* __restrict__ beta,
    const float* __restrict__ mu, const float* __restrict__ var,
    float* __restrict__ Wcat, float* __restrict__ bias2)
{
    const int oc = blockIdx.x;
    const int ic = threadIdx.x;
    float a  = gamma[ic] * rsqrtf(var[ic] + 1e-5f);
    float bb = beta[ic] - mu[ic] * a;
    float w1 = comb_w[(size_t)oc * 512 + ic];
    float w2 = comb_w[(size_t)oc * 512 + 256 + ic];
    Wcat[(size_t)oc * 512 + ic]       = w1;
    Wcat[(size_t)oc * 512 + 256 + ic] = w2 * a;
    float s = w2 * bb;
#pragma unroll
    for (int off = 32; off; off >>= 1) s += __shfl_xor(s, off);
    __shared__ float red[4];
    if ((threadIdx.x & 63) == 0) red[threadIdx.x >> 6] = s;
    __syncthreads();
    if (threadIdx.x == 0)
        bias2[oc] = comb_b[oc] + red[0] + red[1] + red[2] + red[3];
}

// ---------------- comb 1x1 conv as GEMM: out = Wcat @ [f; fin] + bias2 ----------------
__global__ __launch_bounds__(256) void comb_gemm_kernel(
    const float* __restrict__ f,    // [2][256][HW]
    const float* __restrict__ fin,  // [2][256][HW]
    const float* __restrict__ Wcat, // [256][512]
    const float* __restrict__ bias2,// [256]
    float* __restrict__ out, int HW)
{
    const int tid = threadIdx.x;
    const int p0  = blockIdx.x * 64;
    const int oc0 = blockIdx.y * 64;
    const int b   = blockIdx.z;
    __shared__ float s_w[64][16];
    __shared__ float s_x[16][64];
    const int tx = tid & 15, ty = tid >> 4;
    float acc[4][4];
#pragma unroll
    for (int i = 0; i < 4; ++i)
#pragma unroll
        for (int j = 0; j < 4; ++j) acc[i][j] = 0.f;

    for (int k0 = 0; k0 < 512; k0 += 16) {
        {
            int r = tid >> 2, c4 = (tid & 3) * 4;
            *(float4*)&s_w[r][c4] = *(const float4*)&Wcat[(size_t)(oc0 + r) * 512 + k0 + c4];
        }
        {
            int r = tid >> 4, c4 = (tid & 15) * 4;
            int k = k0 + r;
            const float* src = (k < 256)
                ? &f[((size_t)(b * 256 + k)) * HW + p0 + c4]
                : &fin[((size_t)(b * 256 + (k - 256))) * HW + p0 + c4];
            *(float4*)&s_x[r][c4] = *(const float4*)src;
        }
        __syncthreads();
#pragma unroll
        for (int kk = 0; kk < 16; ++kk) {
            float xv[4], wv[4];
#pragma unroll
            for (int j = 0; j < 4; ++j) xv[j] = s_x[kk][tx + 16 * j];
#pragma unroll
            for (int i = 0; i < 4; ++i) wv[i] = s_w[ty + 16 * i][kk];
#pragma unroll
            for (int i = 0; i < 4; ++i)
#pragma unroll
                for (int j = 0; j < 4; ++j) acc[i][j] += wv[i] * xv[j];
        }
        __syncthreads();
    }
#pragma unroll
    for (int i = 0; i < 4; ++i) {
        int oc = oc0 + ty + 16 * i;
        float bs = bias2[oc];
#pragma unroll
        for (int j = 0; j < 4; ++j)
            out[((size_t)(b * 256 + oc)) * HW + p0 + tx + 16 * j] = acc[i][j] + bs;
    }
}

// ---------------- host orchestration ----------------
extern "C" void kernel_launch(void* const* d_in, const int* in_sizes, int n_in,
                              void* d_out, int out_size, void* d_ws, size_t ws_size,
                              hipStream_t stream) {
    if (ws_size < WS_BYTES) return;

    const float* feats[5];
    for (int i = 0; i < 5; ++i) feats[i] = (const float*)d_in[i];
    const float* attn     = (const float*)d_in[5];
    const float* key_t_w  = (const float*)d_in[6];
    const float* key_t_b  = (const float*)d_in[7];
    const float* val_t_w  = (const float*)d_in[8];
    const float* val_t_b  = (const float*)d_in[9];
    const float* key_q_w  = (const float*)d_in[10];
    const float* key_q_b  = (const float*)d_in[11];
    const float* val_q_w  = (const float*)d_in[12];
    const float* val_q_b  = (const float*)d_in[13];
    const float* bn_gamma = (const float*)d_in[14];
    const float* bn_beta  = (const float*)d_in[15];
    const float* comb_w   = (const float*)d_in[16];
    const float* comb_b   = (const float*)d_in[17];

    char* ws = (char*)d_ws;
    unsigned short* kt_hi = (unsigned short*)(ws + B_KTHI);
    unsigned short* kt_lo = (unsigned short*)(ws + B_KTLO);
    unsigned short* vt_bf = (unsigned short*)(ws + B_VTBF);
    unsigned short* kq_hi = (unsigned short*)(ws + B_KQHI);
    unsigned short* kq_lo = (unsigned short*)(ws + B_KQLO);
    unsigned short* vq_bf = (unsigned short*)(ws + B_VQBF);
    float* mean_f   = (float*)(ws + B_MEAN);
    float* fr       = (float*)(ws + B_FR);
    float* fin_part = (float*)(ws + B_FPART);
    float* fin_big  = (float*)(ws + B_FBIG);
    float* fin_sm   = (float*)(ws + B_FSM);
    float* mu       = (float*)(ws + B_MU);
    float* var      = (float*)(ws + B_VAR);
    float* Wcat     = (float*)(ws + B_WCAT);
    float* bias2    = (float*)(ws + B_BIAS2);

    // Stage A: key_t / val_t convs on attentions (bf16 hi/lo + bf16 outputs)
    conv3x3_dual_bf16<<<dim3(20, 20, 4), 256, 0, stream>>>(
        attn, key_t_w, key_t_b, kt_hi, kt_lo, val_t_w, val_t_b, vt_bf);

    static const int HH[5] = {128, 64, 32, 16, 8};
    size_t out_off = 0;
    for (int idx = 0; idx < 5; ++idx) {
        const int H = HH[idx], HW = H * H;
        const float* f = feats[idx];

        mean2d_kernel<<<512, 256, 0, stream>>>(f, mean_f, HW);

        resize_kernel<<<(2 * 256 * 1024) / 256, 256, 0, stream>>>(
            f, fr, mean_f, H, H, 32, 32, 2 * 256 * 1024);

        conv3x3_dual_bf16<<<dim3(2, 20, 4), 256, 0, stream>>>(
            fr,
            key_q_w + (size_t)idx * 32 * 256 * 9,  key_q_b + idx * 32,
            kq_hi, kq_lo,
            val_q_w + (size_t)idx * 128 * 256 * 9, val_q_b + idx * 128,
            vq_bf);

        flash_mfma<<<dim3(8, 2, 20), 256, 0, stream>>>(
            kt_hi, kt_lo, vt_bf, kq_hi, kq_lo, vq_bf, fin_part);

        reduce20_kernel<<<2048, 256, 0, stream>>>(fin_part, fin_sm);

        resize_kernel<<<(2 * 256 * HW + 255) / 256, 256, 0, stream>>>(
            fin_sm, fin_big, nullptr, 32, 32, H, H, 2 * 256 * HW);

        bnstats_kernel<<<256, 256, 0, stream>>>(fin_big, mu, var, HW);

        prep_kernel<<<256, 256, 0, stream>>>(
            comb_w, comb_b, bn_gamma + idx * 256, bn_beta + idx * 256, mu, var, Wcat, bias2);

        comb_gemm_kernel<<<dim3(HW / 64, 4, 2), 256, 0, stream>>>(
            f, fin_big, Wcat, bias2, (float*)d_out + out_off, HW);

        out_off += (size_t)2 * 256 * HW;
    }
}

// Round 3
// 1955.311 us; speedup vs baseline: 5.6946x; 1.7640x over previous
//
#include <hip/hip_runtime.h>
#include <cstddef>
#include <cstdint>

typedef __attribute__((ext_vector_type(4))) short bf16x4;
typedef __attribute__((ext_vector_type(8))) short bf16x8;
typedef __attribute__((ext_vector_type(16))) float f32x16;
typedef __attribute__((ext_vector_type(4))) unsigned short us4;

// ---------------- workspace layout (byte offsets) ----------------
static const size_t B_WPH   = 0;           // 6*9*160*256*2 = 4,423,680
static const size_t B_WPL   = 4423680;     // 4,423,680
static const size_t B_BIASC = 8847360;     // 6*160*4 = 3,840
static const size_t B_KTH   = 8851200;     // 20*1024*32*2 = 1,310,720
static const size_t B_KTL   = 10161920;    // 1,310,720
static const size_t B_VT    = 11472640;    // 20*128*1024*2 = 5,242,880
static const size_t B_KQH   = 16715520;    // 2*1024*32*2 = 131,072
static const size_t B_KQL   = 16846592;    // 131,072
static const size_t B_VQ    = 16977664;    // 2*128*1024*2 = 524,288
static const size_t B_MEAN  = 17501952;    // 2,048
static const size_t B_FR    = 17504000;    // 2*256*1024*4 = 2,097,152
static const size_t B_UNION = 19601152;    // max(fin_part u16 20,971,520 ; fin_big f32 33,554,432)
static const size_t B_FSM   = 53155584;    // 2*256*1024*4 = 2,097,152
static const size_t B_MU    = 55252736;    // 1,024
static const size_t B_VAR   = 55253760;    // 1,024
static const size_t B_WC    = 55254784;    // 256*512*2 = 262,144
static const size_t B_BIAS2 = 55516928;    // 1,024
static const size_t WS_BYTES = 55517952;   // ~55.5 MB

// ---------------- bf16 helpers (RNE) ----------------
__device__ inline unsigned short f2bf(float x) {
    unsigned u = __float_as_uint(x);
    return (unsigned short)((u + 0x7fffu + ((u >> 16) & 1u)) >> 16);
}
__device__ inline float bf2f(unsigned short u) {
    return __uint_as_float(((unsigned)u) << 16);
}
__device__ inline void bf16split(float x, unsigned short& hi, unsigned short& lo) {
    unsigned u = __float_as_uint(x);
    unsigned hb = (u + 0x7fffu + ((u >> 16) & 1u)) >> 16;
    hi = (unsigned short)hb;
    float hf = __uint_as_float(hb << 16);
    float r = x - hf;
    unsigned ur = __float_as_uint(r);
    lo = (unsigned short)((ur + 0x7fffu + ((ur >> 16) & 1u)) >> 16);
}
__device__ inline bf16x8 ld_b64x2(const short* p) {   // 8B-aligned 16B load
    bf16x4 a = *(const bf16x4*)p;
    bf16x4 b = *(const bf16x4*)(p + 4);
    return __builtin_shufflevector(a, b, 0, 1, 2, 3, 4, 5, 6, 7);
}
__device__ inline void st_b64x2(short* p, bf16x8 v) { // 8B-aligned 16B store
    *(bf16x4*)p       = __builtin_shufflevector(v, v, 0, 1, 2, 3);
    *(bf16x4*)(p + 4) = __builtin_shufflevector(v, v, 4, 5, 6, 7);
}

// ---------------- weight pre-transform: [oc][ic][3][3] fp32 -> [set][tap][160][256] bf16 hi/lo ----------------
__global__ __launch_bounds__(256) void prep_weights(
    const float* __restrict__ kt_w, const float* __restrict__ kt_b,
    const float* __restrict__ vt_w, const float* __restrict__ vt_b,
    const float* __restrict__ kq_w, const float* __restrict__ kq_b,
    const float* __restrict__ vq_w, const float* __restrict__ vq_b,
    short* __restrict__ wp_hi, short* __restrict__ wp_lo, float* __restrict__ biasc)
{
    const int oc = blockIdx.x;    // 0..159
    const int s  = blockIdx.y;    // 0..5 (0 = stage A, 1+idx = level)
    const int ic = threadIdx.x;   // 0..255
    const bool iskey = oc < 32;
    const int ocl = iskey ? oc : oc - 32;
    const float* w = iskey
        ? (s == 0 ? kt_w : kq_w + (size_t)(s - 1) * 32 * 256 * 9)
        : (s == 0 ? vt_w : vq_w + (size_t)(s - 1) * 128 * 256 * 9);
    const float* wsrc = w + ((size_t)ocl * 256 + ic) * 9;
#pragma unroll
    for (int t = 0; t < 9; ++t) {
        unsigned short h, l; bf16split(wsrc[t], h, l);
        size_t d = ((size_t)(s * 9 + t) * 160 + oc) * 256 + ic;
        wp_hi[d] = (short)h; wp_lo[d] = (short)l;
    }
    if (ic == 0) {
        const float* bptr = iskey
            ? (s == 0 ? kt_b : kq_b + (s - 1) * 32)
            : (s == 0 ? vt_b : vq_b + (s - 1) * 128);
        biasc[s * 160 + oc] = bptr[ocl];
    }
}

// ---------------- MFMA 3x3 SAME conv on 32x32 images ----------------
// ISKEY: 32 oc, split-bf16 (3 combos), writes transposed [img][1024][32] hi/lo
// !ISKEY: 128 oc, plain bf16, writes natural [img][128][1024]
// grid: (NIMG, 4 bands of 8 rows), block 256 = 4 waves (wave owns 2 rows)
template<bool ISKEY>
__global__ __launch_bounds__(256, 1) void conv3x3_mfma(
    const float* __restrict__ in,     // [NIMG][256][1024] fp32
    const short* __restrict__ wp_hi,  // set base: [9][160][256]
    const short* __restrict__ wp_lo,
    const float* __restrict__ biasc,  // set base [160]
    unsigned short* __restrict__ o_hi,
    unsigned short* __restrict__ o_lo,
    unsigned short* __restrict__ o_v)
{
    constexpr int OCC = ISKEY ? 32 : 128;
    constexpr int OCB = ISKEY ? 0 : 32;
    constexpr int NW  = ISKEY ? 2 : 1;
    constexpr int NACC = ISKEY ? 2 : 8;
    __shared__ short s_x[2][10 * 34 * 16];
    __shared__ short s_w[NW][3 * OCC * 20];

    const int tid = threadIdx.x;
    const int img = blockIdx.x;
    const int band = blockIdx.y;
    const int wv = tid >> 6, l31 = tid & 31, lh = (tid >> 5) & 1;

    f32x16 acc[NACC];
#pragma unroll
    for (int i = 0; i < NACC; ++i)
#pragma unroll
        for (int r = 0; r < 16; ++r) acc[i][r] = 0.f;

    const float* inb = in + (size_t)img * 256 * 1024;

    for (int ic0 = 0; ic0 < 256; ic0 += 16) {
        __syncthreads();
        // x-halo zeros
        if (tid < 40) {
            int r = tid >> 2, side = (tid >> 1) & 1, hl = tid & 1;
            short* d = &s_x[hl][(r * 34 + side * 33) * 16];
#pragma unroll
            for (int i = 0; i < 16; ++i) d[i] = 0;
        }
        // stage X: rows r 0..9 (y = band*8 + r - 1), x 0..31, 16 ic, split hi/lo
        for (int u = tid; u < 320; u += 256) {
            int r = u >> 5, xl = u & 31;
            int y = band * 8 + r - 1;
            short* dh = &s_x[0][(r * 34 + xl + 1) * 16];
            short* dl = &s_x[1][(r * 34 + xl + 1) * 16];
            if ((unsigned)y < 32u) {
                const float* src = inb + (size_t)ic0 * 1024 + y * 32 + xl;
#pragma unroll
                for (int i = 0; i < 16; ++i) {
                    unsigned short h, l; bf16split(src[(size_t)i * 1024], h, l);
                    dh[i] = (short)h; dl[i] = (short)l;
                }
            } else {
#pragma unroll
                for (int i = 0; i < 16; ++i) { dh[i] = 0; dl[i] = 0; }
            }
        }
        for (int tg = 0; tg < 3; ++tg) {           // tap row dy = tg
            if (tg) __syncthreads();
            // stage W: taps tg*3+0..2, OCC rows, 16 ic (rows padded to 20)
            for (int u = tid; u < 3 * OCC * 2; u += 256) {
                int tl = u / (OCC * 2), rem = u - tl * (OCC * 2);
                int o = rem >> 1, h = rem & 1;
                size_t g = ((size_t)((tg * 3 + tl) * 160 + OCB + o)) * 256 + ic0 + h * 8;
                st_b64x2(&s_w[0][(tl * OCC + o) * 20 + h * 8], *(const bf16x8*)&wp_hi[g]);
                if (ISKEY)
                    st_b64x2(&s_w[NW - 1][(tl * OCC + o) * 20 + h * 8], *(const bf16x8*)&wp_lo[g]);
            }
            __syncthreads();
#pragma unroll
            for (int tl = 0; tl < 3; ++tl) {       // tap col dx = tl
                if (ISKEY) {
                    bf16x8 ah = ld_b64x2(&s_w[0][(tl * 32 + l31) * 20 + lh * 8]);
                    bf16x8 al = ld_b64x2(&s_w[NW - 1][(tl * 32 + l31) * 20 + lh * 8]);
#pragma unroll
                    for (int nt = 0; nt < 2; ++nt) {
                        int ri = wv * 2 + nt + tg;
                        int xb = l31 + tl;
                        bf16x8 bh = *(const bf16x8*)&s_x[0][(ri * 34 + xb) * 16 + lh * 8];
                        bf16x8 bl = *(const bf16x8*)&s_x[1][(ri * 34 + xb) * 16 + lh * 8];
                        acc[nt] = __builtin_amdgcn_mfma_f32_32x32x16_bf16(ah, bh, acc[nt], 0, 0, 0);
                        acc[nt] = __builtin_amdgcn_mfma_f32_32x32x16_bf16(ah, bl, acc[nt], 0, 0, 0);
                        acc[nt] = __builtin_amdgcn_mfma_f32_32x32x16_bf16(al, bh, acc[nt], 0, 0, 0);
                    }
                } else {
                    bf16x8 a0 = ld_b64x2(&s_w[0][(tl * 128 +  0 + l31) * 20 + lh * 8]);
                    bf16x8 a1 = ld_b64x2(&s_w[0][(tl * 128 + 32 + l31) * 20 + lh * 8]);
                    bf16x8 a2 = ld_b64x2(&s_w[0][(tl * 128 + 64 + l31) * 20 + lh * 8]);
                    bf16x8 a3 = ld_b64x2(&s_w[0][(tl * 128 + 96 + l31) * 20 + lh * 8]);
#pragma unroll
                    for (int nt = 0; nt < 2; ++nt) {
                        int ri = wv * 2 + nt + tg;
                        int xb = l31 + tl;
                        bf16x8 bh = *(const bf16x8*)&s_x[0][(ri * 34 + xb) * 16 + lh * 8];
                        acc[0 + nt] = __builtin_amdgcn_mfma_f32_32x32x16_bf16(a0, bh, acc[0 + nt], 0, 0, 0);
                        acc[2 + nt] = __builtin_amdgcn_mfma_f32_32x32x16_bf16(a1, bh, acc[2 + nt], 0, 0, 0);
                        acc[4 + nt] = __builtin_amdgcn_mfma_f32_32x32x16_bf16(a2, bh, acc[4 + nt], 0, 0, 0);
                        acc[6 + nt] = __builtin_amdgcn_mfma_f32_32x32x16_bf16(a3, bh, acc[6 + nt], 0, 0, 0);
                    }
                }
            }
        }
    }
    // epilogue
    const int ytop = band * 8 + wv * 2;
    if (ISKEY) {
#pragma unroll
        for (int nt = 0; nt < 2; ++nt) {
            int p = (ytop + nt) * 32 + l31;
            size_t base = ((size_t)img * 1024 + p) * 32;
#pragma unroll
            for (int qd = 0; qd < 4; ++qd) {
                int ocq = 8 * qd + 4 * lh;
                us4 h4, l4;
#pragma unroll
                for (int j = 0; j < 4; ++j) {
                    unsigned short h, l;
                    bf16split(acc[nt][qd * 4 + j] + biasc[ocq + j], h, l);
                    h4[j] = h; l4[j] = l;
                }
                *(us4*)&o_hi[base + ocq] = h4;
                *(us4*)&o_lo[base + ocq] = l4;
            }
        }
    } else {
#pragma unroll
        for (int mt = 0; mt < 4; ++mt)
#pragma unroll
        for (int nt = 0; nt < 2; ++nt) {
            int p = (ytop + nt) * 32 + l31;
#pragma unroll
            for (int r = 0; r < 16; ++r) {
                int vo = mt * 32 + (r & 3) + 8 * (r >> 2) + 4 * lh;
                o_v[((size_t)img * 128 + vo) * 1024 + p] = f2bf(acc[mt * 2 + nt][r] + biasc[32 + vo]);
            }
        }
    }
}

// ---------------- per (b,c) spatial mean ----------------
__global__ __launch_bounds__(256) void mean2d_kernel(
    const float* __restrict__ f, float* __restrict__ mean, int HW)
{
    const int bc = blockIdx.x;
    const float* src = f + (size_t)bc * HW;
    float s = 0.f;
    for (int i = threadIdx.x; i < HW; i += 256) s += src[i];
#pragma unroll
    for (int off = 32; off; off >>= 1) s += __shfl_xor(s, off);
    __shared__ float red[4];
    if ((threadIdx.x & 63) == 0) red[threadIdx.x >> 6] = s;
    __syncthreads();
    if (threadIdx.x == 0)
        mean[bc] = (red[0] + red[1] + red[2] + red[3]) / (float)HW;
}

// ---------------- align-corners bilinear resize (optional mean subtract) ----------------
__global__ __launch_bounds__(256) void resize_kernel(
    const float* __restrict__ in, float* __restrict__ out,
    const float* __restrict__ mean, int ih, int iw, int oh, int ow, int total)
{
    int idx = blockIdx.x * 256 + threadIdx.x;
    if (idx >= total) return;
    int x  = idx % ow;
    int y  = (idx / ow) % oh;
    int bc = idx / (ow * oh);
    float fy = (float)y * (float)(ih - 1) / (float)(oh - 1);
    float fx = (float)x * (float)(iw - 1) / (float)(ow - 1);
    int y0 = (int)fy; int y1 = min(y0 + 1, ih - 1); float wy = fy - (float)y0;
    int x0 = (int)fx; int x1 = min(x0 + 1, iw - 1); float wx = fx - (float)x0;
    const float* p = in + (size_t)bc * ih * iw;
    float a = p[y0 * iw + x0], b = p[y1 * iw + x0];
    float c = p[y0 * iw + x1], d = p[y1 * iw + x1];
    float c0 = a + (b - a) * wy;
    float c1 = c + (d - c) * wy;
    float v  = c0 + (c1 - c0) * wx;
    if (mean) v -= mean[bc];
    out[idx] = v;
}

// ---------------- MFMA flash relation-attention ----------------
// grid: (8 t-tiles of 128, 2 b, 20 n), block 256 = 4 waves
__global__ __launch_bounds__(256, 1) void flash_mfma(
    const unsigned short* __restrict__ kt_hi, const unsigned short* __restrict__ kt_lo,
    const unsigned short* __restrict__ vt_bf,
    const unsigned short* __restrict__ kq_hi, const unsigned short* __restrict__ kq_lo,
    const unsigned short* __restrict__ vq_bf,
    unsigned short* __restrict__ fin_part)   // [20][2][256][1024] bf16
{
    __shared__ unsigned short s_kt_h[128 * 40];
    __shared__ unsigned short s_kt_l[128 * 40];
    __shared__ unsigned short s_kq_h[32 * 40];
    __shared__ unsigned short s_kq_l[32 * 40];
    __shared__ unsigned short s_v[256 * 40];

    const int tid = threadIdx.x;
    const int t0  = blockIdx.x * 128;
    const int b   = blockIdx.y;
    const int n   = blockIdx.z;
    const int wave = tid >> 6;
    const int lane = tid & 63;
    const int l31  = lane & 31;
    const int lh   = lane >> 5;

    for (int c = tid; c < 512; c += 256) {
        int r = c >> 2, h = c & 3;
        size_t goff = ((size_t)(n * 1024 + t0 + r)) * 32 + h * 8;
        *(bf16x8*)&s_kt_h[r * 40 + h * 8] = *(const bf16x8*)&kt_hi[goff];
        *(bf16x8*)&s_kt_l[r * 40 + h * 8] = *(const bf16x8*)&kt_lo[goff];
    }
    __syncthreads();

    bf16x8 btk_h[2], btk_l[2];
    const int trow = wave * 32 + l31;
#pragma unroll
    for (int kh = 0; kh < 2; ++kh) {
        btk_h[kh] = *(const bf16x8*)&s_kt_h[trow * 40 + kh * 16 + lh * 8];
        btk_l[kh] = *(const bf16x8*)&s_kt_l[trow * 40 + kh * 16 + lh * 8];
    }

    f32x16 acc[8] = {};
    float m = -3.0e38f, l = 0.f;

    for (int q0 = 0; q0 < 1024; q0 += 32) {
        {
            int c = tid & 127;
            int r = c >> 2, h = c & 3;
            size_t goff = ((size_t)(b * 1024 + q0 + r)) * 32 + h * 8;
            const unsigned short* src = (tid < 128) ? kq_hi : kq_lo;
            unsigned short* dst = (tid < 128) ? s_kq_h : s_kq_l;
            *(bf16x8*)&dst[r * 40 + h * 8] = *(const bf16x8*)&src[goff];
        }
        {
            const unsigned short* src = (tid < 128)
                ? &vq_bf[((size_t)(b * 128 + tid)) * 1024 + q0]
                : &vt_bf[((size_t)(n * 128 + (tid - 128))) * 1024 + q0];
            unsigned short* dst = &s_v[tid * 40];
#pragma unroll
            for (int c = 0; c < 4; ++c)
                *(bf16x8*)&dst[c * 8] = *(const bf16x8*)&src[c * 8];
        }
        __syncthreads();

        f32x16 s = {};
#pragma unroll
        for (int kh = 0; kh < 2; ++kh) {
            bf16x8 ah = *(const bf16x8*)&s_kq_h[l31 * 40 + kh * 16 + lh * 8];
            bf16x8 al = *(const bf16x8*)&s_kq_l[l31 * 40 + kh * 16 + lh * 8];
            s = __builtin_amdgcn_mfma_f32_32x32x16_bf16(ah, btk_h[kh], s, 0, 0, 0);
            s = __builtin_amdgcn_mfma_f32_32x32x16_bf16(ah, btk_l[kh], s, 0, 0, 0);
            s = __builtin_amdgcn_mfma_f32_32x32x16_bf16(al, btk_h[kh], s, 0, 0, 0);
        }

        float pmax = s[0];
#pragma unroll
        for (int r = 1; r < 16; ++r) pmax = fmaxf(pmax, s[r]);
        pmax = fmaxf(pmax, __shfl_xor(pmax, 32));
        if (!__all(pmax <= m + 8.f)) {
            float mnew = fmaxf(m, pmax);
            float sc = __expf(m - mnew);
            m = mnew;
            l *= sc;
#pragma unroll
            for (int vs = 0; vs < 8; ++vs) acc[vs] *= sc;
        }
        float pv[16]; float ps = 0.f;
#pragma unroll
        for (int r = 0; r < 16; ++r) { pv[r] = __expf(s[r] - m); ps += pv[r]; }
        ps += __shfl_xor(ps, 32);
        l += ps;

        unsigned a0, a1, a2, a3, c0, c1, c2, c3;
        asm("v_cvt_pk_bf16_f32 %0, %1, %2" : "=v"(a0) : "v"(pv[0]),  "v"(pv[1]));
        asm("v_cvt_pk_bf16_f32 %0, %1, %2" : "=v"(a1) : "v"(pv[2]),  "v"(pv[3]));
        asm("v_cvt_pk_bf16_f32 %0, %1, %2" : "=v"(a2) : "v"(pv[4]),  "v"(pv[5]));
        asm("v_cvt_pk_bf16_f32 %0, %1, %2" : "=v"(a3) : "v"(pv[6]),  "v"(pv[7]));
        asm("v_cvt_pk_bf16_f32 %0, %1, %2" : "=v"(c0) : "v"(pv[8]),  "v"(pv[9]));
        asm("v_cvt_pk_bf16_f32 %0, %1, %2" : "=v"(c1) : "v"(pv[10]), "v"(pv[11]));
        asm("v_cvt_pk_bf16_f32 %0, %1, %2" : "=v"(c2) : "v"(pv[12]), "v"(pv[13]));
        asm("v_cvt_pk_bf16_f32 %0, %1, %2" : "=v"(c3) : "v"(pv[14]), "v"(pv[15]));
        asm("v_permlane32_swap_b32 %0, %1" : "+v"(a0), "+v"(a2));
        asm("v_permlane32_swap_b32 %0, %1" : "+v"(a1), "+v"(a3));
        asm("v_permlane32_swap_b32 %0, %1" : "+v"(c0), "+v"(c2));
        asm("v_permlane32_swap_b32 %0, %1" : "+v"(c1), "+v"(c3));
        union { unsigned u[4]; bf16x8 v; } f0, f1;
        f0.u[0] = a0; f0.u[1] = a1; f0.u[2] = a2; f0.u[3] = a3;
        f1.u[0] = c0; f1.u[1] = c1; f1.u[2] = c2; f1.u[3] = c3;

#pragma unroll
        for (int vs = 0; vs < 8; ++vs) {
            const unsigned short* vr = &s_v[(vs * 32 + l31) * 40 + lh * 8];
            bf16x8 va0 = *(const bf16x8*)&vr[0];
            bf16x8 va1 = *(const bf16x8*)&vr[16];
            acc[vs] = __builtin_amdgcn_mfma_f32_32x32x16_bf16(va0, f0.v, acc[vs], 0, 0, 0);
            acc[vs] = __builtin_amdgcn_mfma_f32_32x32x16_bf16(va1, f1.v, acc[vs], 0, 0, 0);
        }
        __syncthreads();
    }

    float linv = 1.f / l;
    unsigned short* outp = fin_part + ((size_t)(n * 2 + b)) * 256 * 1024;
    const int tg = t0 + wave * 32 + l31;
#pragma unroll
    for (int vs = 0; vs < 8; ++vs) {
#pragma unroll
        for (int r = 0; r < 16; ++r) {
            int v = vs * 32 + (r & 3) + 8 * (r >> 2) + 4 * lh;
            outp[(size_t)v * 1024 + tg] = f2bf(acc[vs][r] * linv);
        }
    }
}

// ---------------- sum 20 bf16 n-slabs -> fp32 ----------------
__global__ __launch_bounds__(256) void reduce20_kernel(
    const unsigned short* __restrict__ part, float* __restrict__ out)
{
    size_t i = (size_t)blockIdx.x * 256 + threadIdx.x;
    float s = 0.f;
#pragma unroll
    for (int nn = 0; nn < 20; ++nn) s += bf2f(part[(size_t)nn * 524288 + i]);
    out[i] = s;
}

// ---------------- BN stats over (b, spatial) per channel ----------------
__global__ __launch_bounds__(256) void bnstats_kernel(
    const float* __restrict__ fin, float* __restrict__ mu, float* __restrict__ var, int HW)
{
    const int c = blockIdx.x;
    float s = 0.f, s2 = 0.f;
    for (int b = 0; b < 2; ++b) {
        const float* p = fin + ((size_t)b * 256 + c) * HW;
        for (int i = threadIdx.x; i < HW; i += 256) {
            float v = p[i]; s += v; s2 += v * v;
        }
    }
#pragma unroll
    for (int off = 32; off; off >>= 1) {
        s  += __shfl_xor(s, off);
        s2 += __shfl_xor(s2, off);
    }
    __shared__ float r1[4], r2[4];
    if ((threadIdx.x & 63) == 0) { r1[threadIdx.x >> 6] = s; r2[threadIdx.x >> 6] = s2; }
    __syncthreads();
    if (threadIdx.x == 0) {
        float cnt = 2.f * (float)HW;
        float mm = (r1[0] + r1[1] + r1[2] + r1[3]) / cnt;
        float qq = (r2[0] + r2[1] + r2[2] + r2[3]) / cnt;
        mu[c] = mm; var[c] = qq - mm * mm;
    }
}

// ---------------- fold BN into comb weights -> bf16 Wc + fp32 bias2 ----------------
__global__ __launch_bounds__(256) void prep_comb(
    const float* __restrict__ comb_w, const float* __restrict__ comb_b,
    const float* __restrict__ gamma, const float* __restrict__ beta,
    const float* __restrict__ mu, const float* __restrict__ var,
    short* __restrict__ wc, float* __restrict__ bias2)
{
    const int oc = blockIdx.x;
    const int ic = threadIdx.x;
    float a  = gamma[ic] * rsqrtf(var[ic] + 1e-5f);
    float bb = beta[ic] - mu[ic] * a;
    float w1 = comb_w[(size_t)oc * 512 + ic];
    float w2 = comb_w[(size_t)oc * 512 + 256 + ic];
    wc[(size_t)oc * 512 + ic]       = (short)f2bf(w1);
    wc[(size_t)oc * 512 + 256 + ic] = (short)f2bf(w2 * a);
    float s = w2 * bb;
#pragma unroll
    for (int off = 32; off; off >>= 1) s += __shfl_xor(s, off);
    __shared__ float red[4];
    if ((threadIdx.x & 63) == 0) red[threadIdx.x >> 6] = s;
    __syncthreads();
    if (threadIdx.x == 0)
        bias2[oc] = comb_b[oc] + red[0] + red[1] + red[2] + red[3];
}

// ---------------- comb 1x1 conv as MFMA GEMM: out[256][n] = Wc[256][512] @ X[512][n] ----------------
// grid: (ceil(HW/128), 2 b), block 256 = 4 waves (wm: M-half 128, wn: N-half 64)
__global__ __launch_bounds__(256, 1) void comb_mfma(
    const float* __restrict__ f,    // [2][256][HW]
    const float* __restrict__ fin,  // [2][256][HW]
    const short* __restrict__ wc,   // [256][512] bf16
    const float* __restrict__ bias2,
    float* __restrict__ out, int HW)
{
    __shared__ short s_wc[256 * 40];
    __shared__ short s_xc[128 * 40];
    const int tid = threadIdx.x;
    const int p0 = blockIdx.x * 128;
    const int b  = blockIdx.y;
    const int wv = tid >> 6, l31 = tid & 31, lh = (tid >> 5) & 1;
    const int wm = wv >> 1, wn = wv & 1;

    f32x16 acc[4][2];
#pragma unroll
    for (int i = 0; i < 4; ++i)
#pragma unroll
        for (int j = 0; j < 2; ++j)
#pragma unroll
            for (int r = 0; r < 16; ++r) acc[i][j][r] = 0.f;

    for (int k0 = 0; k0 < 512; k0 += 32) {
        __syncthreads();
        for (int u = tid; u < 512; u += 256) {          // W: 256 rows x 32 k
            int r = u >> 1, h = u & 1;
            *(bf16x8*)&s_wc[r * 40 + h * 16 + 0] = *(const bf16x8*)&wc[(size_t)r * 512 + k0 + h * 16];
            *(bf16x8*)&s_wc[r * 40 + h * 16 + 8] = *(const bf16x8*)&wc[(size_t)r * 512 + k0 + h * 16 + 8];
        }
        for (int u = tid; u < 1024; u += 256) {         // X: 32 k x 128 n (transpose to [n][k])
            int kr = u >> 5, n4 = (u & 31) * 4;
            int ck = k0 + kr;
            const float* bsrc = (ck < 256)
                ? f   + ((size_t)(b * 256 + ck)) * HW
                : fin + ((size_t)(b * 256 + ck - 256)) * HW;
            int p = p0 + n4;
            float v0, v1, v2, v3;
            if (p + 3 < HW) {
                float4 v4 = *(const float4*)&bsrc[p];
                v0 = v4.x; v1 = v4.y; v2 = v4.z; v3 = v4.w;
            } else {
                v0 = bsrc[min(p,     HW - 1)];
                v1 = bsrc[min(p + 1, HW - 1)];
                v2 = bsrc[min(p + 2, HW - 1)];
                v3 = bsrc[min(p + 3, HW - 1)];
            }
            s_xc[(n4 + 0) * 40 + kr] = (short)f2bf(v0);
            s_xc[(n4 + 1) * 40 + kr] = (short)f2bf(v1);
            s_xc[(n4 + 2) * 40 + kr] = (short)f2bf(v2);
            s_xc[(n4 + 3) * 40 + kr] = (short)f2bf(v3);
        }
        __syncthreads();
#pragma unroll
        for (int ks = 0; ks < 2; ++ks) {
            bf16x8 a[4], bx[2];
#pragma unroll
            for (int mi = 0; mi < 4; ++mi)
                a[mi] = *(const bf16x8*)&s_wc[(wm * 128 + mi * 32 + l31) * 40 + ks * 16 + lh * 8];
#pragma unroll
            for (int ni = 0; ni < 2; ++ni)
                bx[ni] = *(const bf16x8*)&s_xc[(wn * 64 + ni * 32 + l31) * 40 + ks * 16 + lh * 8];
#pragma unroll
            for (int mi = 0; mi < 4; ++mi)
#pragma unroll
                for (int ni = 0; ni < 2; ++ni)
                    acc[mi][ni] = __builtin_amdgcn_mfma_f32_32x32x16_bf16(a[mi], bx[ni], acc[mi][ni], 0, 0, 0);
        }
    }
#pragma unroll
    for (int mi = 0; mi < 4; ++mi) {
#pragma unroll
        for (int ni = 0; ni < 2; ++ni) {
            int p = p0 + wn * 64 + ni * 32 + l31;
            if (p < HW) {
#pragma unroll
                for (int r = 0; r < 16; ++r) {
                    int oc = wm * 128 + mi * 32 + (r & 3) + 8 * (r >> 2) + 4 * lh;
                    out[((size_t)(b * 256 + oc)) * HW + p] = acc[mi][ni][r] + bias2[oc];
                }
            }
        }
    }
}

// ---------------- host orchestration ----------------
extern "C" void kernel_launch(void* const* d_in, const int* in_sizes, int n_in,
                              void* d_out, int out_size, void* d_ws, size_t ws_size,
                              hipStream_t stream) {
    if (ws_size < WS_BYTES) return;

    const float* feats[5];
    for (int i = 0; i < 5; ++i) feats[i] = (const float*)d_in[i];
    const float* attn     = (const float*)d_in[5];
    const float* key_t_w  = (const float*)d_in[6];
    const float* key_t_b  = (const float*)d_in[7];
    const float* val_t_w  = (const float*)d_in[8];
    const float* val_t_b  = (const float*)d_in[9];
    const float* key_q_w  = (const float*)d_in[10];
    const float* key_q_b  = (const float*)d_in[11];
    const float* val_q_w  = (const float*)d_in[12];
    const float* val_q_b  = (const float*)d_in[13];
    const float* bn_gamma = (const float*)d_in[14];
    const float* bn_beta  = (const float*)d_in[15];
    const float* comb_w   = (const float*)d_in[16];
    const float* comb_b   = (const float*)d_in[17];

    char* ws = (char*)d_ws;
    short* wp_hi = (short*)(ws + B_WPH);
    short* wp_lo = (short*)(ws + B_WPL);
    float* biasc = (float*)(ws + B_BIASC);
    unsigned short* kt_hi = (unsigned short*)(ws + B_KTH);
    unsigned short* kt_lo = (unsigned short*)(ws + B_KTL);
    unsigned short* vt_bf = (unsigned short*)(ws + B_VT);
    unsigned short* kq_hi = (unsigned short*)(ws + B_KQH);
    unsigned short* kq_lo = (unsigned short*)(ws + B_KQL);
    unsigned short* vq_bf = (unsigned short*)(ws + B_VQ);
    float* mean_f = (float*)(ws + B_MEAN);
    float* fr     = (float*)(ws + B_FR);
    unsigned short* fin_part = (unsigned short*)(ws + B_UNION);
    float* fin_big = (float*)(ws + B_UNION);
    float* fin_sm  = (float*)(ws + B_FSM);
    float* mu     = (float*)(ws + B_MU);
    float* var    = (float*)(ws + B_VAR);
    short* wc_bf  = (short*)(ws + B_WC);
    float* bias2  = (float*)(ws + B_BIAS2);

    prep_weights<<<dim3(160, 6), 256, 0, stream>>>(
        key_t_w, key_t_b, val_t_w, val_t_b, key_q_w, key_q_b, val_q_w, val_q_b,
        wp_hi, wp_lo, biasc);

    // Stage A: key_t / val_t convs on attentions
    conv3x3_mfma<true><<<dim3(20, 4), 256, 0, stream>>>(
        attn, wp_hi, wp_lo, biasc, kt_hi, kt_lo, nullptr);
    conv3x3_mfma<false><<<dim3(20, 4), 256, 0, stream>>>(
        attn, wp_hi, wp_lo, biasc, nullptr, nullptr, vt_bf);

    static const int HH[5] = {128, 64, 32, 16, 8};
    size_t out_off = 0;
    for (int idx = 0; idx < 5; ++idx) {
        const int H = HH[idx], HW = H * H;
        const float* f = feats[idx];
        const size_t wset = (size_t)(1 + idx) * 9 * 160 * 256;
        const float* bset = biasc + (1 + idx) * 160;

        mean2d_kernel<<<512, 256, 0, stream>>>(f, mean_f, HW);
        resize_kernel<<<(2 * 256 * 1024) / 256, 256, 0, stream>>>(
            f, fr, mean_f, H, H, 32, 32, 2 * 256 * 1024);

        conv3x3_mfma<true><<<dim3(2, 4), 256, 0, stream>>>(
            fr, wp_hi + wset, wp_lo + wset, bset, kq_hi, kq_lo, nullptr);
        conv3x3_mfma<false><<<dim3(2, 4), 256, 0, stream>>>(
            fr, wp_hi + wset, wp_lo + wset, bset, nullptr, nullptr, vq_bf);

        flash_mfma<<<dim3(8, 2, 20), 256, 0, stream>>>(
            kt_hi, kt_lo, vt_bf, kq_hi, kq_lo, vq_bf, fin_part);

        reduce20_kernel<<<2048, 256, 0, stream>>>(fin_part, fin_sm);

        resize_kernel<<<(2 * 256 * HW + 255) / 256, 256, 0, stream>>>(
            fin_sm, fin_big, nullptr, 32, 32, H, H, 2 * 256 * HW);

        bnstats_kernel<<<256, 256, 0, stream>>>(fin_big, mu, var, HW);

        prep_comb<<<256, 256, 0, stream>>>(
            comb_w, comb_b, bn_gamma + idx * 256, bn_beta + idx * 256, mu, var, wc_bf, bias2);

        comb_mfma<<<dim3((HW + 127) / 128, 2), 256, 0, stream>>>(
            f, fin_big, wc_bf, bias2, (float*)d_out + out_off, HW);

        out_off += (size_t)2 * 256 * HW;
    }
}

// Round 4
// 1340.075 us; speedup vs baseline: 8.3090x; 1.4591x over previous
//
#include <hip/hip_runtime.h>
#include <cstddef>
#include <cstdint>

typedef __attribute__((ext_vector_type(8))) short bf16x8;
typedef __attribute__((ext_vector_type(16))) float f32x16;
typedef __attribute__((ext_vector_type(4))) unsigned short us4;

// ---------------- workspace layout (byte offsets) ----------------
static const size_t B_WPH   = 0;            // 6*9*160*256*2 = 4,423,680
static const size_t B_WPL   = 4423680;      // 4,423,680
static const size_t B_BIASC = 8847360;      // 6*160*4 = 3,840
static const size_t B_KTH   = 8851200;      // 20*1024*32*2 = 1,310,720
static const size_t B_KTL   = 10161920;     // 1,310,720
static const size_t B_VT    = 11472640;     // 20*128*1024*2 = 5,242,880
static const size_t B_KQH   = 16715520;     // 2*1024*32*2 = 131,072
static const size_t B_KQL   = 16846592;     // 131,072
static const size_t B_VQ    = 16977664;     // 2*128*1024*2 = 524,288
static const size_t B_MEAN  = 17501952;     // 2,048
static const size_t B_FSM   = 17504000;     // 2*256*1024*4 = 2,097,152
static const size_t B_MU    = 19601152;     // 1,024
static const size_t B_VAR   = 19602176;     // 1,024
static const size_t B_WC    = 19603200;     // 256*512*2 = 262,144
static const size_t B_BIAS2 = 19865344;     // 1,024
static const size_t B_UNION = 19866368;     // 33,554,432 union region
//   stage A : attnT_h at U+0 (10,485,760), attnT_l at U+10,485,760
//   level   : frT_h U+0 (1,048,576), frT_l U+1,048,576 ; fin_part U+2,097,152 (20,971,520)
//             fin_big U+0 (up to 33,554,432) after fin_part is dead
static const size_t WS_BYTES = 53420800;

// ---------------- bf16 helpers (RNE) ----------------
__device__ inline unsigned short f2bf(float x) {
    unsigned u = __float_as_uint(x);
    return (unsigned short)((u + 0x7fffu + ((u >> 16) & 1u)) >> 16);
}
__device__ inline float bf2f(unsigned short u) {
    return __uint_as_float(((unsigned)u) << 16);
}
__device__ inline void bf16split(float x, unsigned short& hi, unsigned short& lo) {
    unsigned u = __float_as_uint(x);
    unsigned hb = (u + 0x7fffu + ((u >> 16) & 1u)) >> 16;
    hi = (unsigned short)hb;
    float hf = __uint_as_float(hb << 16);
    float r = x - hf;
    unsigned ur = __float_as_uint(r);
    lo = (unsigned short)((ur + 0x7fffu + ((ur >> 16) & 1u)) >> 16);
}

// ---------------- weight pre-transform ----------------
// [oc][ic][3][3] fp32 -> [set][tap][160][256] bf16 hi/lo; key sets>=1 scaled by log2(e)
__global__ __launch_bounds__(256) void prep_weights(
    const float* __restrict__ kt_w, const float* __restrict__ kt_b,
    const float* __restrict__ vt_w, const float* __restrict__ vt_b,
    const float* __restrict__ kq_w, const float* __restrict__ kq_b,
    const float* __restrict__ vq_w, const float* __restrict__ vq_b,
    short* __restrict__ wp_hi, short* __restrict__ wp_lo, float* __restrict__ biasc)
{
    const int oc = blockIdx.x;    // 0..159
    const int s  = blockIdx.y;    // 0..5 (0 = stage A, 1+idx = level)
    const int ic = threadIdx.x;   // 0..255
    const bool iskey = oc < 32;
    const int ocl = iskey ? oc : oc - 32;
    const float scale = (iskey && s > 0) ? 1.4426950408889634f : 1.0f;
    const float* w = iskey
        ? (s == 0 ? kt_w : kq_w + (size_t)(s - 1) * 32 * 256 * 9)
        : (s == 0 ? vt_w : vq_w + (size_t)(s - 1) * 128 * 256 * 9);
    const float* wsrc = w + ((size_t)ocl * 256 + ic) * 9;
#pragma unroll
    for (int t = 0; t < 9; ++t) {
        unsigned short h, l; bf16split(wsrc[t] * scale, h, l);
        size_t d = ((size_t)(s * 9 + t) * 160 + oc) * 256 + ic;
        wp_hi[d] = (short)h; wp_lo[d] = (short)l;
    }
    if (ic == 0) {
        const float* bptr = iskey
            ? (s == 0 ? kt_b : kq_b + (s - 1) * 32)
            : (s == 0 ? vt_b : vq_b + (s - 1) * 128);
        biasc[s * 160 + oc] = bptr[ocl] * scale;
    }
}

// ---------------- fp32 [N][256][1024] -> bf16 hi/lo [N][16][1024][16] ----------------
__global__ __launch_bounds__(256) void transpose_split(
    const float* __restrict__ in,
    unsigned short* __restrict__ oh, unsigned short* __restrict__ ol)
{
    __shared__ float s[16][260];
    const int n = blockIdx.x, ch = blockIdx.y, p0 = blockIdx.z * 256;
    const int tid = threadIdx.x;
#pragma unroll
    for (int i = 0; i < 16; ++i)
        s[i][tid] = in[((size_t)(n * 256 + ch * 16 + i)) * 1024 + p0 + tid];
    __syncthreads();
    union { unsigned short u[16]; bf16x8 v[2]; } h8, l8;
#pragma unroll
    for (int i = 0; i < 16; ++i) bf16split(s[i][tid], h8.u[i], l8.u[i]);
    size_t base = ((size_t)(n * 16 + ch) * 1024 + p0 + tid) * 16;
    *(bf16x8*)&oh[base] = h8.v[0]; *(bf16x8*)&oh[base + 8] = h8.v[1];
    *(bf16x8*)&ol[base] = l8.v[0]; *(bf16x8*)&ol[base + 8] = l8.v[1];
}

// ---------------- per (b,c) spatial mean ----------------
__global__ __launch_bounds__(256) void mean2d_kernel(
    const float* __restrict__ f, float* __restrict__ mean, int HW)
{
    const int bc = blockIdx.x;
    const float* src = f + (size_t)bc * HW;
    float s = 0.f;
    for (int i = threadIdx.x; i < HW; i += 256) s += src[i];
#pragma unroll
    for (int off = 32; off; off >>= 1) s += __shfl_xor(s, off);
    __shared__ float red[4];
    if ((threadIdx.x & 63) == 0) red[threadIdx.x >> 6] = s;
    __syncthreads();
    if (threadIdx.x == 0)
        mean[bc] = (red[0] + red[1] + red[2] + red[3]) / (float)HW;
}

// ---------------- bilinear resize (HxH -> 32x32) + mean-sub, transposed-split out ----------------
__global__ __launch_bounds__(256) void resizeT_kernel(
    const float* __restrict__ f, const float* __restrict__ mean,
    unsigned short* __restrict__ oh, unsigned short* __restrict__ ol, int H)
{
    __shared__ float s[16][260];
    const int b = blockIdx.x, ch = blockIdx.y, p0 = blockIdx.z * 256;
    const int tid = threadIdx.x;
    const int p = p0 + tid, y = p >> 5, x = p & 31;
    float fy = (float)y * (float)(H - 1) / 31.0f;
    float fx = (float)x * (float)(H - 1) / 31.0f;
    int y0 = (int)fy; int y1 = min(y0 + 1, H - 1); float wy = fy - (float)y0;
    int x0 = (int)fx; int x1 = min(x0 + 1, H - 1); float wx = fx - (float)x0;
#pragma unroll
    for (int i = 0; i < 16; ++i) {
        int c = ch * 16 + i;
        const float* pf = f + ((size_t)(b * 256 + c)) * H * H;
        float a = pf[y0 * H + x0], bb = pf[y1 * H + x0];
        float cc = pf[y0 * H + x1], d = pf[y1 * H + x1];
        float c0 = a + (bb - a) * wy;
        float c1 = cc + (d - cc) * wy;
        s[i][tid] = c0 + (c1 - c0) * wx - mean[b * 256 + c];
    }
    __syncthreads();
    union { unsigned short u[16]; bf16x8 v[2]; } h8, l8;
#pragma unroll
    for (int i = 0; i < 16; ++i) bf16split(s[i][tid], h8.u[i], l8.u[i]);
    size_t base = ((size_t)(b * 16 + ch) * 1024 + p) * 16;
    *(bf16x8*)&oh[base] = h8.v[0]; *(bf16x8*)&oh[base + 8] = h8.v[1];
    *(bf16x8*)&ol[base] = l8.v[0]; *(bf16x8*)&ol[base + 8] = l8.v[1];
}

// ---------------- LDS-free direct MFMA 3x3 SAME conv on 32x32 ----------------
// grid (NIMG, 4, 5): z=0 key (32oc, split 3-combo, transposed hi/lo out),
//                    z=1..4 val (32oc each, plain bf16, natural out)
__global__ __launch_bounds__(256) void conv3x3_direct(
    const unsigned short* __restrict__ xT_h,  // [NIMG][16][1024][16]
    const unsigned short* __restrict__ xT_l,
    const short* __restrict__ wp_hi,          // set base: [9][160][256]
    const short* __restrict__ wp_lo,
    const float* __restrict__ biasc,          // set base [160]
    unsigned short* __restrict__ o_hi,        // key: [NIMG][1024][32]
    unsigned short* __restrict__ o_lo,
    unsigned short* __restrict__ o_v)         // val: [NIMG][128][1024]
{
    const int tid = threadIdx.x;
    const int img = blockIdx.x;
    const int grp = blockIdx.z;
    const bool iskey = (grp == 0);
    const int ocb = grp * 32;                 // biasc base for this group
    const int wave = tid >> 6, l31 = tid & 31, lh = (tid >> 5) & 1;
    const int yp = blockIdx.y * 4 + wave;     // 0..15
    const int y0 = yp * 2;

    f32x16 acc0 = {}, acc1 = {};
    const bf16x8 bz = {};
    const unsigned short* xh = xT_h + (size_t)img * 16 * 16384;
    const unsigned short* xl = xT_l + (size_t)img * 16 * 16384;

    for (int ch = 0; ch < 16; ++ch) {
        const unsigned short* xhc = xh + (size_t)ch * 16384 + lh * 8;
        const unsigned short* xlc = xl + (size_t)ch * 16384 + lh * 8;
#pragma unroll
        for (int tg = 0; tg < 3; ++tg) {
            bf16x8 wh[3], wl[3];
#pragma unroll
            for (int tl = 0; tl < 3; ++tl) {
                size_t wi = ((size_t)((tg * 3 + tl) * 160 + ocb + l31)) * 256 + ch * 16 + lh * 8;
                wh[tl] = *(const bf16x8*)&wp_hi[wi];
                if (iskey) wl[tl] = *(const bf16x8*)&wp_lo[wi];
            }
#pragma unroll
            for (int nt = 0; nt < 2; ++nt) {
                const int ri = y0 + nt - 1 + tg;
                const bool rok = (ri >= 0 && ri < 32);
#pragma unroll
                for (int tl = 0; tl < 3; ++tl) {
                    const int x = l31 + tl - 1;
                    const bool ok = rok && (x >= 0) && (x < 32);
                    bf16x8 bh = bz, bl = bz;
                    if (ok) {
                        const int p = ri * 32 + x;
                        bh = *(const bf16x8*)&xhc[p * 16];
                        if (iskey) bl = *(const bf16x8*)&xlc[p * 16];
                    }
                    f32x16& a = nt ? acc1 : acc0;
                    a = __builtin_amdgcn_mfma_f32_32x32x16_bf16(wh[tl], bh, a, 0, 0, 0);
                    if (iskey) {
                        a = __builtin_amdgcn_mfma_f32_32x32x16_bf16(wh[tl], bl, a, 0, 0, 0);
                        a = __builtin_amdgcn_mfma_f32_32x32x16_bf16(wl[tl], bh, a, 0, 0, 0);
                    }
                }
            }
        }
    }
    // epilogue
    if (iskey) {
#pragma unroll
        for (int nt = 0; nt < 2; ++nt) {
            const f32x16& a = nt ? acc1 : acc0;
            int p = (y0 + nt) * 32 + l31;
            size_t base = ((size_t)img * 1024 + p) * 32;
#pragma unroll
            for (int qd = 0; qd < 4; ++qd) {
                int ocq = 8 * qd + 4 * lh;
                us4 h4, l4;
#pragma unroll
                for (int j = 0; j < 4; ++j) {
                    unsigned short h, l;
                    bf16split(a[qd * 4 + j] + biasc[ocq + j], h, l);
                    h4[j] = h; l4[j] = l;
                }
                *(us4*)&o_hi[base + ocq] = h4;
                *(us4*)&o_lo[base + ocq] = l4;
            }
        }
    } else {
#pragma unroll
        for (int nt = 0; nt < 2; ++nt) {
            const f32x16& a = nt ? acc1 : acc0;
            int p = (y0 + nt) * 32 + l31;
#pragma unroll
            for (int r = 0; r < 16; ++r) {
                int pat = (r & 3) + 8 * (r >> 2) + 4 * lh;
                int vo = (ocb - 32) + pat;
                o_v[((size_t)img * 128 + vo) * 1024 + p] = f2bf(a[r] + biasc[ocb + pat]);
            }
        }
    }
}

// ---------------- flash relation-attention v2 ----------------
// grid (16 t-tiles of 64, 2 b, 20 n), block 256 = 4 waves: tw = w&1 (t-half), vw = w>>1 (v-half)
__global__ __launch_bounds__(256, 3) void flash2(
    const unsigned short* __restrict__ kt_hi, const unsigned short* __restrict__ kt_lo,
    const unsigned short* __restrict__ vt_bf,
    const unsigned short* __restrict__ kq_hi, const unsigned short* __restrict__ kq_lo,
    const unsigned short* __restrict__ vq_bf,
    unsigned short* __restrict__ fin_part)   // [20][2][256][1024] bf16
{
    __shared__ unsigned short s_v[256 * 40];
    const int tid = threadIdx.x;
    const int t0 = blockIdx.x * 64;
    const int b  = blockIdx.y;
    const int n  = blockIdx.z;
    const int wave = tid >> 6, lane = tid & 63, l31 = lane & 31, lh = lane >> 5;
    const int tw = wave & 1, vw = wave >> 1;

    // hoisted key_t B-fragments (constant for the whole q loop)
    const int trow = t0 + tw * 32 + l31;
    bf16x8 btk_h0, btk_h1, btk_l0, btk_l1;
    {
        size_t g = ((size_t)n * 1024 + trow) * 32 + lh * 8;
        btk_h0 = *(const bf16x8*)&kt_hi[g];
        btk_h1 = *(const bf16x8*)&kt_hi[g + 16];
        btk_l0 = *(const bf16x8*)&kt_lo[g];
        btk_l1 = *(const bf16x8*)&kt_lo[g + 16];
    }

    // V source row for this thread (row tid of the 256-row V block)
    const unsigned short* vsrc = (tid < 128)
        ? &vq_bf[((size_t)b * 128 + tid) * 1024]
        : &vt_bf[((size_t)n * 128 + (tid - 128)) * 1024];
    const unsigned short* kqh = kq_hi + (size_t)b * 1024 * 32;
    const unsigned short* kql = kq_lo + (size_t)b * 1024 * 32;

    // prefetch q0 = 0
    bf16x8 nv0 = *(const bf16x8*)&vsrc[0];
    bf16x8 nv1 = *(const bf16x8*)&vsrc[8];
    bf16x8 nv2 = *(const bf16x8*)&vsrc[16];
    bf16x8 nv3 = *(const bf16x8*)&vsrc[24];
    bf16x8 nah0 = *(const bf16x8*)&kqh[(size_t)l31 * 32 + lh * 8];
    bf16x8 nah1 = *(const bf16x8*)&kqh[(size_t)l31 * 32 + 16 + lh * 8];
    bf16x8 nal0 = *(const bf16x8*)&kql[(size_t)l31 * 32 + lh * 8];
    bf16x8 nal1 = *(const bf16x8*)&kql[(size_t)l31 * 32 + 16 + lh * 8];

    f32x16 acc0 = {}, acc1 = {}, acc2 = {}, acc3 = {};
    float m = -3.0e38f, lsum = 0.f;

    for (int q0 = 0; q0 < 1024; q0 += 32) {
        __syncthreads();
        {
            unsigned short* dst = &s_v[tid * 40];
            *(bf16x8*)&dst[0]  = nv0;
            *(bf16x8*)&dst[8]  = nv1;
            *(bf16x8*)&dst[16] = nv2;
            *(bf16x8*)&dst[24] = nv3;
        }
        bf16x8 ah0 = nah0, ah1 = nah1, al0 = nal0, al1 = nal1;
        __syncthreads();

        if (q0 + 32 < 1024) {   // prefetch next step (overlaps with compute below)
            const int qn = q0 + 32;
            nv0 = *(const bf16x8*)&vsrc[qn];
            nv1 = *(const bf16x8*)&vsrc[qn + 8];
            nv2 = *(const bf16x8*)&vsrc[qn + 16];
            nv3 = *(const bf16x8*)&vsrc[qn + 24];
            size_t kb = (size_t)(qn + l31) * 32 + lh * 8;
            nah0 = *(const bf16x8*)&kqh[kb];
            nah1 = *(const bf16x8*)&kqh[kb + 16];
            nal0 = *(const bf16x8*)&kql[kb];
            nal1 = *(const bf16x8*)&kql[kb + 16];
        }

        // S tile [32 q][32 t] in log2 domain (kq pre-scaled by log2 e)
        f32x16 s = {};
        s = __builtin_amdgcn_mfma_f32_32x32x16_bf16(ah0, btk_h0, s, 0, 0, 0);
        s = __builtin_amdgcn_mfma_f32_32x32x16_bf16(ah0, btk_l0, s, 0, 0, 0);
        s = __builtin_amdgcn_mfma_f32_32x32x16_bf16(al0, btk_h0, s, 0, 0, 0);
        s = __builtin_amdgcn_mfma_f32_32x32x16_bf16(ah1, btk_h1, s, 0, 0, 0);
        s = __builtin_amdgcn_mfma_f32_32x32x16_bf16(ah1, btk_l1, s, 0, 0, 0);
        s = __builtin_amdgcn_mfma_f32_32x32x16_bf16(al1, btk_h1, s, 0, 0, 0);

        // online softmax over q (lane holds one t-column, 16 q rows; partner lane has other 16)
        float pmax = s[0];
#pragma unroll
        for (int r = 1; r < 16; ++r) pmax = fmaxf(pmax, s[r]);
        pmax = fmaxf(pmax, __shfl_xor(pmax, 32));
        if (!__all(pmax <= m + 11.5417f)) {   // defer-max, THR = 8 nats in log2
            float mnew = fmaxf(m, pmax);
            float sc = __builtin_amdgcn_exp2f(m - mnew);
            m = mnew; lsum *= sc;
            acc0 *= sc; acc1 *= sc; acc2 *= sc; acc3 *= sc;
        }
        float pv[16]; float ps = 0.f;
#pragma unroll
        for (int r = 0; r < 16; ++r) { pv[r] = __builtin_amdgcn_exp2f(s[r] - m); ps += pv[r]; }
        lsum += ps;   // lane-partial; merged with partner at epilogue

        // P -> B-operand frags (in-register: cvt_pk + permlane32_swap)
        unsigned a0, a1, a2, a3, c0, c1, c2, c3;
        asm("v_cvt_pk_bf16_f32 %0, %1, %2" : "=v"(a0) : "v"(pv[0]),  "v"(pv[1]));
        asm("v_cvt_pk_bf16_f32 %0, %1, %2" : "=v"(a1) : "v"(pv[2]),  "v"(pv[3]));
        asm("v_cvt_pk_bf16_f32 %0, %1, %2" : "=v"(a2) : "v"(pv[4]),  "v"(pv[5]));
        asm("v_cvt_pk_bf16_f32 %0, %1, %2" : "=v"(a3) : "v"(pv[6]),  "v"(pv[7]));
        asm("v_cvt_pk_bf16_f32 %0, %1, %2" : "=v"(c0) : "v"(pv[8]),  "v"(pv[9]));
        asm("v_cvt_pk_bf16_f32 %0, %1, %2" : "=v"(c1) : "v"(pv[10]), "v"(pv[11]));
        asm("v_cvt_pk_bf16_f32 %0, %1, %2" : "=v"(c2) : "v"(pv[12]), "v"(pv[13]));
        asm("v_cvt_pk_bf16_f32 %0, %1, %2" : "=v"(c3) : "v"(pv[14]), "v"(pv[15]));
        asm("v_permlane32_swap_b32 %0, %1" : "+v"(a0), "+v"(a2));
        asm("v_permlane32_swap_b32 %0, %1" : "+v"(a1), "+v"(a3));
        asm("v_permlane32_swap_b32 %0, %1" : "+v"(c0), "+v"(c2));
        asm("v_permlane32_swap_b32 %0, %1" : "+v"(c1), "+v"(c3));
        union { unsigned u[4]; bf16x8 v; } f0, f1;
        f0.u[0] = a0; f0.u[1] = a1; f0.u[2] = a2; f0.u[3] = a3;
        f1.u[0] = c0; f1.u[1] = c1; f1.u[2] = c2; f1.u[3] = c3;

        // PV: this wave's v-half (128 rows)
#pragma unroll
        for (int vs = 0; vs < 4; ++vs) {
            const unsigned short* vr = &s_v[(vw * 128 + vs * 32 + l31) * 40 + lh * 8];
            bf16x8 va0 = *(const bf16x8*)&vr[0];
            bf16x8 va1 = *(const bf16x8*)&vr[16];
            f32x16& a = (vs == 0) ? acc0 : (vs == 1) ? acc1 : (vs == 2) ? acc2 : acc3;
            a = __builtin_amdgcn_mfma_f32_32x32x16_bf16(va0, f0.v, a, 0, 0, 0);
            a = __builtin_amdgcn_mfma_f32_32x32x16_bf16(va1, f1.v, a, 0, 0, 0);
        }
    }

    float lt = lsum + __shfl_xor(lsum, 32);
    float linv = 1.f / lt;
    unsigned short* outp = fin_part + ((size_t)(n * 2 + b)) * 256 * 1024;
    const int tg = t0 + tw * 32 + l31;
#pragma unroll
    for (int vs = 0; vs < 4; ++vs) {
        const f32x16& a = (vs == 0) ? acc0 : (vs == 1) ? acc1 : (vs == 2) ? acc2 : acc3;
#pragma unroll
        for (int r = 0; r < 16; ++r) {
            int v = vw * 128 + vs * 32 + (r & 3) + 8 * (r >> 2) + 4 * lh;
            outp[(size_t)v * 1024 + tg] = f2bf(a[r] * linv);
        }
    }
}

// ---------------- sum 20 bf16 n-slabs -> fp32 ----------------
__global__ __launch_bounds__(256) void reduce20_kernel(
    const unsigned short* __restrict__ part, float* __restrict__ out)
{
    size_t i = (size_t)blockIdx.x * 256 + threadIdx.x;
    float s = 0.f;
#pragma unroll
    for (int nn = 0; nn < 20; ++nn) s += bf2f(part[(size_t)nn * 524288 + i]);
    out[i] = s;
}

// ---------------- align-corners bilinear resize (32x32 -> HxH), fp32 ----------------
__global__ __launch_bounds__(256) void resize_kernel(
    const float* __restrict__ in, float* __restrict__ out,
    int ih, int iw, int oh, int ow, int total)
{
    int idx = blockIdx.x * 256 + threadIdx.x;
    if (idx >= total) return;
    int x  = idx % ow;
    int y  = (idx / ow) % oh;
    int bc = idx / (ow * oh);
    float fy = (float)y * (float)(ih - 1) / (float)(oh - 1);
    float fx = (float)x * (float)(iw - 1) / (float)(ow - 1);
    int y0 = (int)fy; int y1 = min(y0 + 1, ih - 1); float wy = fy - (float)y0;
    int x0 = (int)fx; int x1 = min(x0 + 1, iw - 1); float wx = fx - (float)x0;
    const float* p = in + (size_t)bc * ih * iw;
    float a = p[y0 * iw + x0], b = p[y1 * iw + x0];
    float c = p[y0 * iw + x1], d = p[y1 * iw + x1];
    float c0 = a + (b - a) * wy;
    float c1 = c + (d - c) * wy;
    out[idx] = c0 + (c1 - c0) * wx;
}

// ---------------- BN stats over (b, spatial) per channel ----------------
__global__ __launch_bounds__(256) void bnstats_kernel(
    const float* __restrict__ fin, float* __restrict__ mu, float* __restrict__ var, int HW)
{
    const int c = blockIdx.x;
    float s = 0.f, s2 = 0.f;
    for (int b = 0; b < 2; ++b) {
        const float* p = fin + ((size_t)b * 256 + c) * HW;
        for (int i = threadIdx.x; i < HW; i += 256) {
            float v = p[i]; s += v; s2 += v * v;
        }
    }
#pragma unroll
    for (int off = 32; off; off >>= 1) {
        s  += __shfl_xor(s, off);
        s2 += __shfl_xor(s2, off);
    }
    __shared__ float r1[4], r2[4];
    if ((threadIdx.x & 63) == 0) { r1[threadIdx.x >> 6] = s; r2[threadIdx.x >> 6] = s2; }
    __syncthreads();
    if (threadIdx.x == 0) {
        float cnt = 2.f * (float)HW;
        float mm = (r1[0] + r1[1] + r1[2] + r1[3]) / cnt;
        float qq = (r2[0] + r2[1] + r2[2] + r2[3]) / cnt;
        mu[c] = mm; var[c] = qq - mm * mm;
    }
}

// ---------------- fold BN into comb weights -> bf16 Wc + fp32 bias2 ----------------
__global__ __launch_bounds__(256) void prep_comb(
    const float* __restrict__ comb_w, const float* __restrict__ comb_b,
    const float* __restrict__ gamma, const float* __restrict__ beta,
    const float* __restrict__ mu, const float* __restrict__ var,
    short* __restrict__ wc, float* __restrict__ bias2)
{
    const int oc = blockIdx.x;
    const int ic = threadIdx.x;
    float a  = gamma[ic] * rsqrtf(var[ic] + 1e-5f);
    float bb = beta[ic] - mu[ic] * a;
    float w1 = comb_w[(size_t)oc * 512 + ic];
    float w2 = comb_w[(size_t)oc * 512 + 256 + ic];
    wc[(size_t)oc * 512 + ic]       = (short)f2bf(w1);
    wc[(size_t)oc * 512 + 256 + ic] = (short)f2bf(w2 * a);
    float s = w2 * bb;
#pragma unroll
    for (int off = 32; off; off >>= 1) s += __shfl_xor(s, off);
    __shared__ float red[4];
    if ((threadIdx.x & 63) == 0) red[threadIdx.x >> 6] = s;
    __syncthreads();
    if (threadIdx.x == 0)
        bias2[oc] = comb_b[oc] + red[0] + red[1] + red[2] + red[3];
}

// ---------------- comb 1x1 conv as MFMA GEMM ----------------
__global__ __launch_bounds__(256, 1) void comb_mfma(
    const float* __restrict__ f,    // [2][256][HW]
    const float* __restrict__ fin,  // [2][256][HW]
    const short* __restrict__ wc,   // [256][512] bf16
    const float* __restrict__ bias2,
    float* __restrict__ out, int HW)
{
    __shared__ short s_wc[256 * 40];
    __shared__ short s_xc[128 * 40];
    const int tid = threadIdx.x;
    const int p0 = blockIdx.x * 128;
    const int b  = blockIdx.y;
    const int wv = tid >> 6, l31 = tid & 31, lh = (tid >> 5) & 1;
    const int wm = wv >> 1, wn = wv & 1;

    f32x16 acc[4][2];
#pragma unroll
    for (int i = 0; i < 4; ++i)
#pragma unroll
        for (int j = 0; j < 2; ++j)
#pragma unroll
            for (int r = 0; r < 16; ++r) acc[i][j][r] = 0.f;

    for (int k0 = 0; k0 < 512; k0 += 32) {
        __syncthreads();
        for (int u = tid; u < 512; u += 256) {
            int r = u >> 1, h = u & 1;
            *(bf16x8*)&s_wc[r * 40 + h * 16 + 0] = *(const bf16x8*)&wc[(size_t)r * 512 + k0 + h * 16];
            *(bf16x8*)&s_wc[r * 40 + h * 16 + 8] = *(const bf16x8*)&wc[(size_t)r * 512 + k0 + h * 16 + 8];
        }
        for (int u = tid; u < 1024; u += 256) {
            int kr = u >> 5, n4 = (u & 31) * 4;
            int ck = k0 + kr;
            const float* bsrc = (ck < 256)
                ? f   + ((size_t)(b * 256 + ck)) * HW
                : fin + ((size_t)(b * 256 + ck - 256)) * HW;
            int p = p0 + n4;
            float v0, v1, v2, v3;
            if (p + 3 < HW) {
                float4 v4 = *(const float4*)&bsrc[p];
                v0 = v4.x; v1 = v4.y; v2 = v4.z; v3 = v4.w;
            } else {
                v0 = bsrc[min(p,     HW - 1)];
                v1 = bsrc[min(p + 1, HW - 1)];
                v2 = bsrc[min(p + 2, HW - 1)];
                v3 = bsrc[min(p + 3, HW - 1)];
            }
            s_xc[(n4 + 0) * 40 + kr] = (short)f2bf(v0);
            s_xc[(n4 + 1) * 40 + kr] = (short)f2bf(v1);
            s_xc[(n4 + 2) * 40 + kr] = (short)f2bf(v2);
            s_xc[(n4 + 3) * 40 + kr] = (short)f2bf(v3);
        }
        __syncthreads();
#pragma unroll
        for (int ks = 0; ks < 2; ++ks) {
            bf16x8 a[4], bx[2];
#pragma unroll
            for (int mi = 0; mi < 4; ++mi)
                a[mi] = *(const bf16x8*)&s_wc[(wm * 128 + mi * 32 + l31) * 40 + ks * 16 + lh * 8];
#pragma unroll
            for (int ni = 0; ni < 2; ++ni)
                bx[ni] = *(const bf16x8*)&s_xc[(wn * 64 + ni * 32 + l31) * 40 + ks * 16 + lh * 8];
#pragma unroll
            for (int mi = 0; mi < 4; ++mi)
#pragma unroll
                for (int ni = 0; ni < 2; ++ni)
                    acc[mi][ni] = __builtin_amdgcn_mfma_f32_32x32x16_bf16(a[mi], bx[ni], acc[mi][ni], 0, 0, 0);
        }
    }
#pragma unroll
    for (int mi = 0; mi < 4; ++mi) {
#pragma unroll
        for (int ni = 0; ni < 2; ++ni) {
            int p = p0 + wn * 64 + ni * 32 + l31;
            if (p < HW) {
#pragma unroll
                for (int r = 0; r < 16; ++r) {
                    int oc = wm * 128 + mi * 32 + (r & 3) + 8 * (r >> 2) + 4 * lh;
                    out[((size_t)(b * 256 + oc)) * HW + p] = acc[mi][ni][r] + bias2[oc];
                }
            }
        }
    }
}

// ---------------- host orchestration ----------------
extern "C" void kernel_launch(void* const* d_in, const int* in_sizes, int n_in,
                              void* d_out, int out_size, void* d_ws, size_t ws_size,
                              hipStream_t stream) {
    if (ws_size < WS_BYTES) return;

    const float* feats[5];
    for (int i = 0; i < 5; ++i) feats[i] = (const float*)d_in[i];
    const float* attn     = (const float*)d_in[5];
    const float* key_t_w  = (const float*)d_in[6];
    const float* key_t_b  = (const float*)d_in[7];
    const float* val_t_w  = (const float*)d_in[8];
    const float* val_t_b  = (const float*)d_in[9];
    const float* key_q_w  = (const float*)d_in[10];
    const float* key_q_b  = (const float*)d_in[11];
    const float* val_q_w  = (const float*)d_in[12];
    const float* val_q_b  = (const float*)d_in[13];
    const float* bn_gamma = (const float*)d_in[14];
    const float* bn_beta  = (const float*)d_in[15];
    const float* comb_w   = (const float*)d_in[16];
    const float* comb_b   = (const float*)d_in[17];

    char* ws = (char*)d_ws;
    short* wp_hi = (short*)(ws + B_WPH);
    short* wp_lo = (short*)(ws + B_WPL);
    float* biasc = (float*)(ws + B_BIASC);
    unsigned short* kt_hi = (unsigned short*)(ws + B_KTH);
    unsigned short* kt_lo = (unsigned short*)(ws + B_KTL);
    unsigned short* vt_bf = (unsigned short*)(ws + B_VT);
    unsigned short* kq_hi = (unsigned short*)(ws + B_KQH);
    unsigned short* kq_lo = (unsigned short*)(ws + B_KQL);
    unsigned short* vq_bf = (unsigned short*)(ws + B_VQ);
    float* mean_f = (float*)(ws + B_MEAN);
    float* fin_sm = (float*)(ws + B_FSM);
    float* mu     = (float*)(ws + B_MU);
    float* var    = (float*)(ws + B_VAR);
    short* wc_bf  = (short*)(ws + B_WC);
    float* bias2  = (float*)(ws + B_BIAS2);
    // union region
    unsigned short* attnT_h = (unsigned short*)(ws + B_UNION);
    unsigned short* attnT_l = (unsigned short*)(ws + B_UNION + 10485760);
    unsigned short* frT_h   = (unsigned short*)(ws + B_UNION);
    unsigned short* frT_l   = (unsigned short*)(ws + B_UNION + 1048576);
    unsigned short* fin_part= (unsigned short*)(ws + B_UNION + 2097152);
    float* fin_big          = (float*)(ws + B_UNION);

    prep_weights<<<dim3(160, 6), 256, 0, stream>>>(
        key_t_w, key_t_b, val_t_w, val_t_b, key_q_w, key_q_b, val_q_w, val_q_b,
        wp_hi, wp_lo, biasc);

    // Stage A: transpose attentions, then key_t / val_t convs
    transpose_split<<<dim3(20, 16, 4), 256, 0, stream>>>(attn, attnT_h, attnT_l);
    conv3x3_direct<<<dim3(20, 4, 5), 256, 0, stream>>>(
        attnT_h, attnT_l, wp_hi, wp_lo, biasc, kt_hi, kt_lo, vt_bf);

    static const int HH[5] = {128, 64, 32, 16, 8};
    size_t out_off = 0;
    for (int idx = 0; idx < 5; ++idx) {
        const int H = HH[idx], HW = H * H;
        const float* f = feats[idx];
        const size_t wset = (size_t)(1 + idx) * 9 * 160 * 256;
        const float* bset = biasc + (1 + idx) * 160;

        mean2d_kernel<<<512, 256, 0, stream>>>(f, mean_f, HW);

        resizeT_kernel<<<dim3(2, 16, 4), 256, 0, stream>>>(f, mean_f, frT_h, frT_l, H);

        conv3x3_direct<<<dim3(2, 4, 5), 256, 0, stream>>>(
            frT_h, frT_l, wp_hi + wset, wp_lo + wset, bset, kq_hi, kq_lo, vq_bf);

        flash2<<<dim3(16, 2, 20), 256, 0, stream>>>(
            kt_hi, kt_lo, vt_bf, kq_hi, kq_lo, vq_bf, fin_part);

        reduce20_kernel<<<2048, 256, 0, stream>>>(fin_part, fin_sm);

        resize_kernel<<<(2 * 256 * HW + 255) / 256, 256, 0, stream>>>(
            fin_sm, fin_big, 32, 32, H, H, 2 * 256 * HW);

        bnstats_kernel<<<256, 256, 0, stream>>>(fin_big, mu, var, HW);

        prep_comb<<<256, 256, 0, stream>>>(
            comb_w, comb_b, bn_gamma + idx * 256, bn_beta + idx * 256, mu, var, wc_bf, bias2);

        comb_mfma<<<dim3((HW + 127) / 128, 2), 256, 0, stream>>>(
            f, fin_big, wc_bf, bias2, (float*)d_out + out_off, HW);

        out_off += (size_t)2 * 256 * HW;
    }
}

// Round 8
// 921.576 us; speedup vs baseline: 12.0822x; 1.4541x over previous
//
#include <hip/hip_runtime.h>
#include <cstddef>
#include <cstdint>

typedef __attribute__((ext_vector_type(8))) short bf16x8;
typedef __attribute__((ext_vector_type(16))) float f32x16;
typedef __attribute__((ext_vector_type(4))) unsigned short us4;

// ---------------- workspace layout (byte offsets) ----------------
static const size_t B_BIASC = 0;            // 6*160*4 = 3,840
static const size_t B_KTH   = 3840;         // 20*1024*32*2 = 1,310,720
static const size_t B_KTL   = 1314560;      // 1,310,720
static const size_t B_VT    = 2625280;      // 20*128*1024*2 = 5,242,880
static const size_t B_KQH   = 7868160;      // 5*2*1024*32*2 = 655,360
static const size_t B_KQL   = 8523520;      // 655,360
static const size_t B_VQ    = 9178880;      // 5*2*128*1024*2 = 2,621,440
static const size_t B_MEAN  = 11800320;     // 5*512*4 = 10,240
static const size_t B_FSM   = 11810560;     // 5*2*256*1024*2 = 5,242,880 (bf16)
static const size_t B_MU    = 17053440;     // 5*256*4 = 5,120
static const size_t B_VAR   = 17058560;     // 5,120
static const size_t B_WC    = 17063680;     // 5*256*512*2 = 1,310,720
static const size_t B_BIAS2 = 18374400;     // 5,120
static const size_t B_UNION = 18379520;     // 40,304,640 union region
// phase 1: X_all_hi +0 (15,728,640), X_all_lo +15,728,640, wp_hi +31,457,280, wp_lo +35,880,960
// phase 2 (per level): fin_part +0 (20*2*256*1024*2 = 20,971,520) -> reduce20 -> fsm;
//                      then fin_big fp32 +0 (<=33,554,432) overwrites it
static const size_t U_XH    = 0;
static const size_t U_XL    = 15728640;
static const size_t U_WPH   = 31457280;
static const size_t U_WPL   = 35880960;
static const size_t U_FPART = 0;
static const size_t WS_BYTES = 58684160;    // ~58.7 MB

// ---------------- bf16 helpers (RNE) ----------------
__device__ inline unsigned short f2bf(float x) {
    unsigned u = __float_as_uint(x);
    return (unsigned short)((u + 0x7fffu + ((u >> 16) & 1u)) >> 16);
}
__device__ inline float bf2f(unsigned short u) {
    return __uint_as_float(((unsigned)u) << 16);
}
__device__ inline void bf16split(float x, unsigned short& hi, unsigned short& lo) {
    unsigned u = __float_as_uint(x);
    unsigned hb = (u + 0x7fffu + ((u >> 16) & 1u)) >> 16;
    hi = (unsigned short)hb;
    float hf = __uint_as_float(hb << 16);
    float r = x - hf;
    unsigned ur = __float_as_uint(r);
    lo = (unsigned short)((ur + 0x7fffu + ((ur >> 16) & 1u)) >> 16);
}
__device__ inline const float* sel5(const float* a, const float* b, const float* c,
                                    const float* d, const float* e, int i) {
    return i == 0 ? a : i == 1 ? b : i == 2 ? c : i == 3 ? d : e;
}

// ---------------- weight pre-transform ----------------
__global__ __launch_bounds__(256) void prep_weights(
    const float* __restrict__ kt_w, const float* __restrict__ kt_b,
    const float* __restrict__ vt_w, const float* __restrict__ vt_b,
    const float* __restrict__ kq_w, const float* __restrict__ kq_b,
    const float* __restrict__ vq_w, const float* __restrict__ vq_b,
    short* __restrict__ wp_hi, short* __restrict__ wp_lo, float* __restrict__ biasc)
{
    const int oc = blockIdx.x;    // 0..159
    const int s  = blockIdx.y;    // 0..5 (0 = stage A, 1+idx = level)
    const int ic = threadIdx.x;   // 0..255
    const bool iskey = oc < 32;
    const int ocl = iskey ? oc : oc - 32;
    const float scale = (iskey && s > 0) ? 1.4426950408889634f : 1.0f;
    const float* w = iskey
        ? (s == 0 ? kt_w : kq_w + (size_t)(s - 1) * 32 * 256 * 9)
        : (s == 0 ? vt_w : vq_w + (size_t)(s - 1) * 128 * 256 * 9);
    const float* wsrc = w + ((size_t)ocl * 256 + ic) * 9;
#pragma unroll
    for (int t = 0; t < 9; ++t) {
        unsigned short h, l; bf16split(wsrc[t] * scale, h, l);
        size_t d = ((size_t)(s * 9 + t) * 160 + oc) * 256 + ic;
        wp_hi[d] = (short)h; wp_lo[d] = (short)l;
    }
    if (ic == 0) {
        const float* bptr = iskey
            ? (s == 0 ? kt_b : kq_b + (s - 1) * 32)
            : (s == 0 ? vt_b : vq_b + (s - 1) * 128);
        biasc[s * 160 + oc] = bptr[ocl] * scale;
    }
}

// ---------------- fp32 [20][256][1024] -> bf16 hi/lo X_all imgs 0..19 ----------------
__global__ __launch_bounds__(256) void transpose_split(
    const float* __restrict__ in,
    unsigned short* __restrict__ oh, unsigned short* __restrict__ ol)
{
    __shared__ float s[16][260];
    const int n = blockIdx.x, ch = blockIdx.y, p0 = blockIdx.z * 256;
    const int tid = threadIdx.x;
#pragma unroll
    for (int i = 0; i < 16; ++i)
        s[i][tid] = in[((size_t)(n * 256 + ch * 16 + i)) * 1024 + p0 + tid];
    __syncthreads();
    union { unsigned short u[16]; bf16x8 v[2]; } h8, l8;
#pragma unroll
    for (int i = 0; i < 16; ++i) bf16split(s[i][tid], h8.u[i], l8.u[i]);
    size_t base = ((size_t)(n * 16 + ch) * 1024 + p0 + tid) * 16;
    *(bf16x8*)&oh[base] = h8.v[0]; *(bf16x8*)&oh[base + 8] = h8.v[1];
    *(bf16x8*)&ol[base] = l8.v[0]; *(bf16x8*)&ol[base + 8] = l8.v[1];
}

// ---------------- batched per (lvl,b,c) spatial mean ----------------
__global__ __launch_bounds__(256) void mean2d_all(
    const float* f0, const float* f1, const float* f2, const float* f3, const float* f4,
    float* __restrict__ mean)
{
    const int lvl = blockIdx.y;
    const float* f = sel5(f0, f1, f2, f3, f4, lvl);
    const int H = 128 >> lvl, HW = H * H;
    const int bc = blockIdx.x;
    const float* src = f + (size_t)bc * HW;
    float s = 0.f;
    for (int i = threadIdx.x; i < HW; i += 256) s += src[i];
#pragma unroll
    for (int off = 32; off; off >>= 1) s += __shfl_xor(s, off);
    __shared__ float red[4];
    if ((threadIdx.x & 63) == 0) red[threadIdx.x >> 6] = s;
    __syncthreads();
    if (threadIdx.x == 0)
        mean[lvl * 512 + bc] = (red[0] + red[1] + red[2] + red[3]) / (float)HW;
}

// ---------------- batched resize (HxH->32x32) + mean-sub -> X_all imgs 20..29 ----------------
__global__ __launch_bounds__(256) void resizeT_all(
    const float* f0, const float* f1, const float* f2, const float* f3, const float* f4,
    const float* __restrict__ mean,
    unsigned short* __restrict__ oh, unsigned short* __restrict__ ol)
{
    __shared__ float s[16][260];
    const int lvl = blockIdx.z >> 2;
    const int p0 = (blockIdx.z & 3) * 256;
    const int b = blockIdx.x, ch = blockIdx.y;
    const float* f = sel5(f0, f1, f2, f3, f4, lvl);
    const int H = 128 >> lvl;
    const int img = 20 + lvl * 2 + b;
    const int tid = threadIdx.x;
    const int p = p0 + tid, y = p >> 5, x = p & 31;
    float fy = (float)y * (float)(H - 1) / 31.0f;
    float fx = (float)x * (float)(H - 1) / 31.0f;
    int y0 = (int)fy; int y1 = min(y0 + 1, H - 1); float wy = fy - (float)y0;
    int x0 = (int)fx; int x1 = min(x0 + 1, H - 1); float wx = fx - (float)x0;
#pragma unroll
    for (int i = 0; i < 16; ++i) {
        int c = ch * 16 + i;
        const float* pf = f + ((size_t)(b * 256 + c)) * H * H;
        float a = pf[y0 * H + x0], bb = pf[y1 * H + x0];
        float cc = pf[y0 * H + x1], d = pf[y1 * H + x1];
        float c0 = a + (bb - a) * wy;
        float c1 = cc + (d - cc) * wy;
        s[i][tid] = c0 + (c1 - c0) * wx - mean[lvl * 512 + b * 256 + c];
    }
    __syncthreads();
    union { unsigned short u[16]; bf16x8 v[2]; } h8, l8;
#pragma unroll
    for (int i = 0; i < 16; ++i) bf16split(s[i][tid], h8.u[i], l8.u[i]);
    size_t base = ((size_t)(img * 16 + ch) * 1024 + p) * 16;
    *(bf16x8*)&oh[base] = h8.v[0]; *(bf16x8*)&oh[base + 8] = h8.v[1];
    *(bf16x8*)&ol[base] = l8.v[0]; *(bf16x8*)&ol[base + 8] = l8.v[1];
}

// ---------------- LDS-free direct MFMA 3x3 SAME conv (round-4 body, batched imgs) ----------------
__global__ __launch_bounds__(256) void conv3x3_direct(
    const unsigned short* __restrict__ xT_h,  // [30][16][1024][16]
    const unsigned short* __restrict__ xT_l,
    const short* __restrict__ wp_hi_all,      // [6][9][160][256]
    const short* __restrict__ wp_lo_all,
    const float* __restrict__ biasc_all,      // [6][160]
    unsigned short* __restrict__ kt_hi, unsigned short* __restrict__ kt_lo,
    unsigned short* __restrict__ vt,
    unsigned short* __restrict__ kq_hi, unsigned short* __restrict__ kq_lo,
    unsigned short* __restrict__ vq)
{
    const int tid = threadIdx.x;
    const int img = blockIdx.x;
    const int grp = blockIdx.z;
    const bool iskey = (grp == 0);
    const int set = (img < 20) ? 0 : 1 + ((img - 20) >> 1);
    const int ocb = grp * 32;
    const int wave = tid >> 6, l31 = tid & 31, lh = (tid >> 5) & 1;
    const int yp = blockIdx.y * 4 + wave;     // 0..15
    const int y0 = yp * 2;

    f32x16 acc0 = {}, acc1 = {};
    const bf16x8 bz = {};
    const unsigned short* xh = xT_h + (size_t)img * 16 * 16384;
    const unsigned short* xl = xT_l + (size_t)img * 16 * 16384;
    const short* wph = wp_hi_all + (size_t)set * 368640;
    const short* wpl = wp_lo_all + (size_t)set * 368640;
    const float* bset = biasc_all + set * 160;

    for (int ch = 0; ch < 16; ++ch) {
        const unsigned short* xhc = xh + (size_t)ch * 16384 + lh * 8;
        const unsigned short* xlc = xl + (size_t)ch * 16384 + lh * 8;
#pragma unroll
        for (int tg = 0; tg < 3; ++tg) {
            bf16x8 wh[3], wl[3];
#pragma unroll
            for (int tl = 0; tl < 3; ++tl) {
                size_t wi = ((size_t)((tg * 3 + tl) * 160 + ocb + l31)) * 256 + (ch << 4) + lh * 8;
                wh[tl] = *(const bf16x8*)&wph[wi];
                if (iskey) wl[tl] = *(const bf16x8*)&wpl[wi];
            }
#pragma unroll
            for (int nt = 0; nt < 2; ++nt) {
                const int ri = y0 + nt - 1 + tg;
                const bool rok = (ri >= 0 && ri < 32);
#pragma unroll
                for (int tl = 0; tl < 3; ++tl) {
                    const int x = l31 + tl - 1;
                    const bool ok = rok && (x >= 0) && (x < 32);
                    bf16x8 bh = bz, bl = bz;
                    if (ok) {
                        const int p = ri * 32 + x;
                        bh = *(const bf16x8*)&xhc[p * 16];
                        if (iskey) bl = *(const bf16x8*)&xlc[p * 16];
                    }
                    f32x16& a = nt ? acc1 : acc0;
                    a = __builtin_amdgcn_mfma_f32_32x32x16_bf16(wh[tl], bh, a, 0, 0, 0);
                    if (iskey) {
                        a = __builtin_amdgcn_mfma_f32_32x32x16_bf16(wh[tl], bl, a, 0, 0, 0);
                        a = __builtin_amdgcn_mfma_f32_32x32x16_bf16(wl[tl], bh, a, 0, 0, 0);
                    }
                }
            }
        }
    }
    if (iskey) {
#pragma unroll
        for (int nt = 0; nt < 2; ++nt) {
            const f32x16& a = nt ? acc1 : acc0;
            int p = (y0 + nt) * 32 + l31;
            size_t base = (img < 20)
                ? ((size_t)img * 1024 + p) * 32
                : ((size_t)(img - 20) * 1024 + p) * 32;
            unsigned short* oh = (img < 20) ? kt_hi : kq_hi;
            unsigned short* ol = (img < 20) ? kt_lo : kq_lo;
#pragma unroll
            for (int qd = 0; qd < 4; ++qd) {
                int ocq = 8 * qd + 4 * lh;
                us4 h4, l4;
#pragma unroll
                for (int j = 0; j < 4; ++j) {
                    unsigned short h, l;
                    bf16split(a[qd * 4 + j] + bset[ocq + j], h, l);
                    h4[j] = h; l4[j] = l;
                }
                *(us4*)&oh[base + ocq] = h4;
                *(us4*)&ol[base + ocq] = l4;
            }
        }
    } else {
        unsigned short* ov = (img < 20) ? vt : vq;
        const int iml = (img < 20) ? img : img - 20;
#pragma unroll
        for (int nt = 0; nt < 2; ++nt) {
            const f32x16& a = nt ? acc1 : acc0;
            int p = (y0 + nt) * 32 + l31;
#pragma unroll
            for (int r = 0; r < 16; ++r) {
                int pat = (r & 3) + 8 * (r >> 2) + 4 * lh;
                int vo = (ocb - 32) + pat;
                ov[((size_t)iml * 128 + vo) * 1024 + p] = f2bf(a[r] + bset[ocb + pat]);
            }
        }
    }
}

// ---------------- flash relation-attention (round-4 flash2, verbatim) ----------------
// grid (16 t-tiles of 64, 2 b, 20 n), block 256 = 4 waves: tw = w&1, vw = w>>1
__global__ __launch_bounds__(256, 3) void flash2(
    const unsigned short* __restrict__ kt_hi, const unsigned short* __restrict__ kt_lo,
    const unsigned short* __restrict__ vt_bf,
    const unsigned short* __restrict__ kq_hi, const unsigned short* __restrict__ kq_lo,
    const unsigned short* __restrict__ vq_bf,
    unsigned short* __restrict__ fin_part)   // [20][2][256][1024] bf16
{
    __shared__ unsigned short s_v[256 * 40];
    const int tid = threadIdx.x;
    const int t0 = blockIdx.x * 64;
    const int b  = blockIdx.y;
    const int n  = blockIdx.z;
    const int wave = tid >> 6, lane = tid & 63, l31 = lane & 31, lh = lane >> 5;
    const int tw = wave & 1, vw = wave >> 1;

    const int trow = t0 + tw * 32 + l31;
    bf16x8 btk_h0, btk_h1, btk_l0, btk_l1;
    {
        size_t g = ((size_t)n * 1024 + trow) * 32 + lh * 8;
        btk_h0 = *(const bf16x8*)&kt_hi[g];
        btk_h1 = *(const bf16x8*)&kt_hi[g + 16];
        btk_l0 = *(const bf16x8*)&kt_lo[g];
        btk_l1 = *(const bf16x8*)&kt_lo[g + 16];
    }

    const unsigned short* vsrc = (tid < 128)
        ? &vq_bf[((size_t)b * 128 + tid) * 1024]
        : &vt_bf[((size_t)n * 128 + (tid - 128)) * 1024];
    const unsigned short* kqh = kq_hi + (size_t)b * 1024 * 32;
    const unsigned short* kql = kq_lo + (size_t)b * 1024 * 32;

    bf16x8 nv0 = *(const bf16x8*)&vsrc[0];
    bf16x8 nv1 = *(const bf16x8*)&vsrc[8];
    bf16x8 nv2 = *(const bf16x8*)&vsrc[16];
    bf16x8 nv3 = *(const bf16x8*)&vsrc[24];
    bf16x8 nah0 = *(const bf16x8*)&kqh[(size_t)l31 * 32 + lh * 8];
    bf16x8 nah1 = *(const bf16x8*)&kqh[(size_t)l31 * 32 + 16 + lh * 8];
    bf16x8 nal0 = *(const bf16x8*)&kql[(size_t)l31 * 32 + lh * 8];
    bf16x8 nal1 = *(const bf16x8*)&kql[(size_t)l31 * 32 + 16 + lh * 8];

    f32x16 acc0 = {}, acc1 = {}, acc2 = {}, acc3 = {};
    float m = -3.0e38f, lsum = 0.f;

    for (int q0 = 0; q0 < 1024; q0 += 32) {
        __syncthreads();
        {
            unsigned short* dst = &s_v[tid * 40];
            *(bf16x8*)&dst[0]  = nv0;
            *(bf16x8*)&dst[8]  = nv1;
            *(bf16x8*)&dst[16] = nv2;
            *(bf16x8*)&dst[24] = nv3;
        }
        bf16x8 ah0 = nah0, ah1 = nah1, al0 = nal0, al1 = nal1;
        __syncthreads();

        if (q0 + 32 < 1024) {
            const int qn = q0 + 32;
            nv0 = *(const bf16x8*)&vsrc[qn];
            nv1 = *(const bf16x8*)&vsrc[qn + 8];
            nv2 = *(const bf16x8*)&vsrc[qn + 16];
            nv3 = *(const bf16x8*)&vsrc[qn + 24];
            size_t kb = (size_t)(qn + l31) * 32 + lh * 8;
            nah0 = *(const bf16x8*)&kqh[kb];
            nah1 = *(const bf16x8*)&kqh[kb + 16];
            nal0 = *(const bf16x8*)&kql[kb];
            nal1 = *(const bf16x8*)&kql[kb + 16];
        }

        // S tile [32 q][32 t] in log2 domain (kq pre-scaled by log2 e)
        f32x16 s = {};
        s = __builtin_amdgcn_mfma_f32_32x32x16_bf16(ah0, btk_h0, s, 0, 0, 0);
        s = __builtin_amdgcn_mfma_f32_32x32x16_bf16(ah0, btk_l0, s, 0, 0, 0);
        s = __builtin_amdgcn_mfma_f32_32x32x16_bf16(al0, btk_h0, s, 0, 0, 0);
        s = __builtin_amdgcn_mfma_f32_32x32x16_bf16(ah1, btk_h1, s, 0, 0, 0);
        s = __builtin_amdgcn_mfma_f32_32x32x16_bf16(ah1, btk_l1, s, 0, 0, 0);
        s = __builtin_amdgcn_mfma_f32_32x32x16_bf16(al1, btk_h1, s, 0, 0, 0);

        float pmax = s[0];
#pragma unroll
        for (int r = 1; r < 16; ++r) pmax = fmaxf(pmax, s[r]);
        pmax = fmaxf(pmax, __shfl_xor(pmax, 32));
        if (!__all(pmax <= m + 11.5417f)) {
            float mnew = fmaxf(m, pmax);
            float sc = __builtin_amdgcn_exp2f(m - mnew);
            m = mnew; lsum *= sc;
            acc0 *= sc; acc1 *= sc; acc2 *= sc; acc3 *= sc;
        }
        float pv[16]; float ps = 0.f;
#pragma unroll
        for (int r = 0; r < 16; ++r) { pv[r] = __builtin_amdgcn_exp2f(s[r] - m); ps += pv[r]; }
        lsum += ps;

        unsigned a0, a1, a2, a3, c0, c1, c2, c3;
        asm("v_cvt_pk_bf16_f32 %0, %1, %2" : "=v"(a0) : "v"(pv[0]),  "v"(pv[1]));
        asm("v_cvt_pk_bf16_f32 %0, %1, %2" : "=v"(a1) : "v"(pv[2]),  "v"(pv[3]));
        asm("v_cvt_pk_bf16_f32 %0, %1, %2" : "=v"(a2) : "v"(pv[4]),  "v"(pv[5]));
        asm("v_cvt_pk_bf16_f32 %0, %1, %2" : "=v"(a3) : "v"(pv[6]),  "v"(pv[7]));
        asm("v_cvt_pk_bf16_f32 %0, %1, %2" : "=v"(c0) : "v"(pv[8]),  "v"(pv[9]));
        asm("v_cvt_pk_bf16_f32 %0, %1, %2" : "=v"(c1) : "v"(pv[10]), "v"(pv[11]));
        asm("v_cvt_pk_bf16_f32 %0, %1, %2" : "=v"(c2) : "v"(pv[12]), "v"(pv[13]));
        asm("v_cvt_pk_bf16_f32 %0, %1, %2" : "=v"(c3) : "v"(pv[14]), "v"(pv[15]));
        asm("v_permlane32_swap_b32 %0, %1" : "+v"(a0), "+v"(a2));
        asm("v_permlane32_swap_b32 %0, %1" : "+v"(a1), "+v"(a3));
        asm("v_permlane32_swap_b32 %0, %1" : "+v"(c0), "+v"(c2));
        asm("v_permlane32_swap_b32 %0, %1" : "+v"(c1), "+v"(c3));
        union { unsigned u[4]; bf16x8 v; } f0, f1;
        f0.u[0] = a0; f0.u[1] = a1; f0.u[2] = a2; f0.u[3] = a3;
        f1.u[0] = c0; f1.u[1] = c1; f1.u[2] = c2; f1.u[3] = c3;

#pragma unroll
        for (int vs = 0; vs < 4; ++vs) {
            const unsigned short* vr = &s_v[(vw * 128 + vs * 32 + l31) * 40 + lh * 8];
            bf16x8 va0 = *(const bf16x8*)&vr[0];
            bf16x8 va1 = *(const bf16x8*)&vr[16];
            f32x16& a = (vs == 0) ? acc0 : (vs == 1) ? acc1 : (vs == 2) ? acc2 : acc3;
            a = __builtin_amdgcn_mfma_f32_32x32x16_bf16(va0, f0.v, a, 0, 0, 0);
            a = __builtin_amdgcn_mfma_f32_32x32x16_bf16(va1, f1.v, a, 0, 0, 0);
        }
    }

    float lt = lsum + __shfl_xor(lsum, 32);
    float linv = 1.f / lt;
    unsigned short* outp = fin_part + ((size_t)(n * 2 + b)) * 256 * 1024;
    const int tg = t0 + tw * 32 + l31;
#pragma unroll
    for (int vs = 0; vs < 4; ++vs) {
        const f32x16& a = (vs == 0) ? acc0 : (vs == 1) ? acc1 : (vs == 2) ? acc2 : acc3;
#pragma unroll
        for (int r = 0; r < 16; ++r) {
            int v = vw * 128 + vs * 32 + (r & 3) + 8 * (r >> 2) + 4 * lh;
            outp[(size_t)v * 1024 + tg] = f2bf(a[r] * linv);
        }
    }
}

// ---------------- sum 20 bf16 n-slabs -> bf16 fsm slice ----------------
__global__ __launch_bounds__(256) void reduce20_bf(
    const unsigned short* __restrict__ part, unsigned short* __restrict__ out)
{
    size_t i = (size_t)blockIdx.x * 256 + threadIdx.x;
    float s = 0.f;
#pragma unroll
    for (int nn = 0; nn < 20; ++nn) s += bf2f(part[(size_t)nn * 524288 + i]);
    out[i] = f2bf(s);
}

// ---------------- bilinear upsample 32x32 -> HxH, bf16 in / fp32 out ----------------
__global__ __launch_bounds__(256) void upsample_bf(
    const unsigned short* __restrict__ in,   // level slice [2][256][1024] bf16
    float* __restrict__ out,                 // [2][256][H][H] fp32
    int oh, int ow, int total)
{
    int idx = blockIdx.x * 256 + threadIdx.x;
    if (idx >= total) return;
    int x  = idx % ow;
    int y  = (idx / ow) % oh;
    int bc = idx / (ow * oh);
    float fy = (float)y * 31.0f / (float)(oh - 1);
    float fx = (float)x * 31.0f / (float)(ow - 1);
    int y0 = (int)fy; int y1 = min(y0 + 1, 31); float wy = fy - (float)y0;
    int x0 = (int)fx; int x1 = min(x0 + 1, 31); float wx = fx - (float)x0;
    const unsigned short* p = in + (size_t)bc * 1024;
    float a = bf2f(p[y0 * 32 + x0]), b = bf2f(p[y1 * 32 + x0]);
    float c = bf2f(p[y0 * 32 + x1]), d = bf2f(p[y1 * 32 + x1]);
    float c0 = a + (b - a) * wy;
    float c1 = c + (d - c) * wy;
    out[idx] = c0 + (c1 - c0) * wx;
}

// ---------------- BN stats over (b, spatial) per channel ----------------
__global__ __launch_bounds__(256) void bnstats_kernel(
    const float* __restrict__ fin, float* __restrict__ mu, float* __restrict__ var, int HW)
{
    const int c = blockIdx.x;
    float s = 0.f, s2 = 0.f;
    for (int b = 0; b < 2; ++b) {
        const float* p = fin + ((size_t)b * 256 + c) * HW;
        for (int i = threadIdx.x; i < HW; i += 256) {
            float v = p[i]; s += v; s2 += v * v;
        }
    }
#pragma unroll
    for (int off = 32; off; off >>= 1) {
        s  += __shfl_xor(s, off);
        s2 += __shfl_xor(s2, off);
    }
    __shared__ float r1[4], r2[4];
    if ((threadIdx.x & 63) == 0) { r1[threadIdx.x >> 6] = s; r2[threadIdx.x >> 6] = s2; }
    __syncthreads();
    if (threadIdx.x == 0) {
        float cnt = 2.f * (float)HW;
        float mm = (r1[0] + r1[1] + r1[2] + r1[3]) / cnt;
        float qq = (r2[0] + r2[1] + r2[2] + r2[3]) / cnt;
        mu[c] = mm; var[c] = qq - mm * mm;
    }
}

// ---------------- fold BN into comb weights ----------------
__global__ __launch_bounds__(256) void prep_comb(
    const float* __restrict__ comb_w, const float* __restrict__ comb_b,
    const float* __restrict__ gamma, const float* __restrict__ beta,
    const float* __restrict__ mu, const float* __restrict__ var,
    short* __restrict__ wc, float* __restrict__ bias2)
{
    const int oc = blockIdx.x;
    const int ic = threadIdx.x;
    float a  = gamma[ic] * rsqrtf(var[ic] + 1e-5f);
    float bb = beta[ic] - mu[ic] * a;
    float w1 = comb_w[(size_t)oc * 512 + ic];
    float w2 = comb_w[(size_t)oc * 512 + 256 + ic];
    wc[(size_t)oc * 512 + ic]       = (short)f2bf(w1);
    wc[(size_t)oc * 512 + 256 + ic] = (short)f2bf(w2 * a);
    float s = w2 * bb;
#pragma unroll
    for (int off = 32; off; off >>= 1) s += __shfl_xor(s, off);
    __shared__ float red[4];
    if ((threadIdx.x & 63) == 0) red[threadIdx.x >> 6] = s;
    __syncthreads();
    if (threadIdx.x == 0)
        bias2[oc] = comb_b[oc] + red[0] + red[1] + red[2] + red[3];
}

// ---------------- comb 1x1 conv as MFMA GEMM (fp32 fin) ----------------
__global__ __launch_bounds__(256, 1) void comb_mfma(
    const float* __restrict__ f,    // [2][256][HW]
    const float* __restrict__ fin,  // [2][256][HW] fp32
    const short* __restrict__ wc,   // [256][512] bf16
    const float* __restrict__ bias2,
    float* __restrict__ out, int HW)
{
    __shared__ short s_wc[256 * 40];
    __shared__ short s_xc[128 * 40];
    const int tid = threadIdx.x;
    const int p0 = blockIdx.x * 128;
    const int b  = blockIdx.y;
    const int wv = tid >> 6, l31 = tid & 31, lh = (tid >> 5) & 1;
    const int wm = wv >> 1, wn = wv & 1;

    f32x16 acc[4][2];
#pragma unroll
    for (int i = 0; i < 4; ++i)
#pragma unroll
        for (int j = 0; j < 2; ++j)
#pragma unroll
            for (int r = 0; r < 16; ++r) acc[i][j][r] = 0.f;

    for (int k0 = 0; k0 < 512; k0 += 32) {
        __syncthreads();
        for (int u = tid; u < 512; u += 256) {
            int r = u >> 1, h = u & 1;
            *(bf16x8*)&s_wc[r * 40 + h * 16 + 0] = *(const bf16x8*)&wc[(size_t)r * 512 + k0 + h * 16];
            *(bf16x8*)&s_wc[r * 40 + h * 16 + 8] = *(const bf16x8*)&wc[(size_t)r * 512 + k0 + h * 16 + 8];
        }
        for (int u = tid; u < 1024; u += 256) {
            int kr = u >> 5, n4 = (u & 31) * 4;
            int ck = k0 + kr;
            const float* bsrc = (ck < 256)
                ? f   + ((size_t)(b * 256 + ck)) * HW
                : fin + ((size_t)(b * 256 + ck - 256)) * HW;
            int p = p0 + n4;
            float v0, v1, v2, v3;
            if (p + 3 < HW) {
                float4 v4 = *(const float4*)&bsrc[p];
                v0 = v4.x; v1 = v4.y; v2 = v4.z; v3 = v4.w;
            } else {
                v0 = bsrc[min(p,     HW - 1)];
                v1 = bsrc[min(p + 1, HW - 1)];
                v2 = bsrc[min(p + 2, HW - 1)];
                v3 = bsrc[min(p + 3, HW - 1)];
            }
            s_xc[(n4 + 0) * 40 + kr] = (short)f2bf(v0);
            s_xc[(n4 + 1) * 40 + kr] = (short)f2bf(v1);
            s_xc[(n4 + 2) * 40 + kr] = (short)f2bf(v2);
            s_xc[(n4 + 3) * 40 + kr] = (short)f2bf(v3);
        }
        __syncthreads();
#pragma unroll
        for (int ks = 0; ks < 2; ++ks) {
            bf16x8 a[4], bx[2];
#pragma unroll
            for (int mi = 0; mi < 4; ++mi)
                a[mi] = *(const bf16x8*)&s_wc[(wm * 128 + mi * 32 + l31) * 40 + ks * 16 + lh * 8];
#pragma unroll
            for (int ni = 0; ni < 2; ++ni)
                bx[ni] = *(const bf16x8*)&s_xc[(wn * 64 + ni * 32 + l31) * 40 + ks * 16 + lh * 8];
#pragma unroll
            for (int mi = 0; mi < 4; ++mi)
#pragma unroll
                for (int ni = 0; ni < 2; ++ni)
                    acc[mi][ni] = __builtin_amdgcn_mfma_f32_32x32x16_bf16(a[mi], bx[ni], acc[mi][ni], 0, 0, 0);
        }
    }
#pragma unroll
    for (int mi = 0; mi < 4; ++mi) {
#pragma unroll
        for (int ni = 0; ni < 2; ++ni) {
            int p = p0 + wn * 64 + ni * 32 + l31;
            if (p < HW) {
#pragma unroll
                for (int r = 0; r < 16; ++r) {
                    int oc = wm * 128 + mi * 32 + (r & 3) + 8 * (r >> 2) + 4 * lh;
                    out[((size_t)(b * 256 + oc)) * HW + p] = acc[mi][ni][r] + bias2[oc];
                }
            }
        }
    }
}

// ---------------- host orchestration ----------------
extern "C" void kernel_launch(void* const* d_in, const int* in_sizes, int n_in,
                              void* d_out, int out_size, void* d_ws, size_t ws_size,
                              hipStream_t stream) {
    if (ws_size < WS_BYTES) return;

    const float* feats[5];
    for (int i = 0; i < 5; ++i) feats[i] = (const float*)d_in[i];
    const float* attn     = (const float*)d_in[5];
    const float* key_t_w  = (const float*)d_in[6];
    const float* key_t_b  = (const float*)d_in[7];
    const float* val_t_w  = (const float*)d_in[8];
    const float* val_t_b  = (const float*)d_in[9];
    const float* key_q_w  = (const float*)d_in[10];
    const float* key_q_b  = (const float*)d_in[11];
    const float* val_q_w  = (const float*)d_in[12];
    const float* val_q_b  = (const float*)d_in[13];
    const float* bn_gamma = (const float*)d_in[14];
    const float* bn_beta  = (const float*)d_in[15];
    const float* comb_w   = (const float*)d_in[16];
    const float* comb_b   = (const float*)d_in[17];

    char* ws = (char*)d_ws;
    float* biasc = (float*)(ws + B_BIASC);
    unsigned short* kt_hi = (unsigned short*)(ws + B_KTH);
    unsigned short* kt_lo = (unsigned short*)(ws + B_KTL);
    unsigned short* vt    = (unsigned short*)(ws + B_VT);
    unsigned short* kq_hi = (unsigned short*)(ws + B_KQH);
    unsigned short* kq_lo = (unsigned short*)(ws + B_KQL);
    unsigned short* vq    = (unsigned short*)(ws + B_VQ);
    float* mean_f = (float*)(ws + B_MEAN);
    unsigned short* fsm = (unsigned short*)(ws + B_FSM);
    float* mu     = (float*)(ws + B_MU);
    float* var    = (float*)(ws + B_VAR);
    short* wc_bf  = (short*)(ws + B_WC);
    float* bias2  = (float*)(ws + B_BIAS2);
    unsigned short* X_h = (unsigned short*)(ws + B_UNION + U_XH);
    unsigned short* X_l = (unsigned short*)(ws + B_UNION + U_XL);
    short* wp_hi = (short*)(ws + B_UNION + U_WPH);
    short* wp_lo = (short*)(ws + B_UNION + U_WPL);
    unsigned short* fin_part = (unsigned short*)(ws + B_UNION + U_FPART);
    float* fin_big = (float*)(ws + B_UNION);   // overwrites fin_part after reduce20

    prep_weights<<<dim3(160, 6), 256, 0, stream>>>(
        key_t_w, key_t_b, val_t_w, val_t_b, key_q_w, key_q_b, val_q_w, val_q_b,
        wp_hi, wp_lo, biasc);

    transpose_split<<<dim3(20, 16, 4), 256, 0, stream>>>(attn, X_h, X_l);

    mean2d_all<<<dim3(512, 5), 256, 0, stream>>>(
        feats[0], feats[1], feats[2], feats[3], feats[4], mean_f);

    resizeT_all<<<dim3(2, 16, 20), 256, 0, stream>>>(
        feats[0], feats[1], feats[2], feats[3], feats[4], mean_f, X_h, X_l);

    conv3x3_direct<<<dim3(30, 4, 5), 256, 0, stream>>>(
        X_h, X_l, wp_hi, wp_lo, biasc, kt_hi, kt_lo, vt, kq_hi, kq_lo, vq);

    size_t out_off = 0;
    for (int idx = 0; idx < 5; ++idx) {
        const int H = 128 >> idx, HW = H * H;
        const int total = 2 * 256 * HW;

        flash2<<<dim3(16, 2, 20), 256, 0, stream>>>(
            kt_hi, kt_lo, vt,
            kq_hi + (size_t)idx * 2 * 32768,
            kq_lo + (size_t)idx * 2 * 32768,
            vq + (size_t)idx * 2 * 131072,
            fin_part);

        reduce20_bf<<<2048, 256, 0, stream>>>(fin_part, fsm + (size_t)idx * 524288);

        upsample_bf<<<(total + 255) / 256, 256, 0, stream>>>(
            fsm + (size_t)idx * 524288, fin_big, H, H, total);

        bnstats_kernel<<<256, 256, 0, stream>>>(fin_big, mu + idx * 256, var + idx * 256, HW);

        prep_comb<<<256, 256, 0, stream>>>(
            comb_w, comb_b, bn_gamma + idx * 256, bn_beta + idx * 256,
            mu + idx * 256, var + idx * 256, wc_bf + (size_t)idx * 131072, bias2 + idx * 256);

        comb_mfma<<<dim3((HW + 127) / 128, 2), 256, 0, stream>>>(
            feats[idx], fin_big, wc_bf + (size_t)idx * 131072, bias2 + idx * 256,
            (float*)d_out + out_off, HW);

        out_off += (size_t)2 * 256 * HW;
    }
}

// Round 9
// 893.866 us; speedup vs baseline: 12.4568x; 1.0310x over previous
//
#include <hip/hip_runtime.h>
#include <cstddef>
#include <cstdint>

typedef __attribute__((ext_vector_type(8))) short bf16x8;
typedef __attribute__((ext_vector_type(16))) float f32x16;
typedef __attribute__((ext_vector_type(4))) unsigned short us4;

// ---------------- workspace layout (byte offsets) ----------------
static const size_t B_BIASC = 0;            // 6*160*4 = 3,840
static const size_t B_KTH   = 3840;         // 20*1024*32*2 = 1,310,720
static const size_t B_KTL   = 1314560;      // 1,310,720
static const size_t B_VT    = 2625280;      // 20*128*1024*2 = 5,242,880
static const size_t B_KQH   = 7868160;      // 5*2*1024*32*2 = 655,360
static const size_t B_KQL   = 8523520;      // 655,360
static const size_t B_VQ    = 9178880;      // 5*2*128*1024*2 = 2,621,440
static const size_t B_MEAN  = 11800320;     // 5*512*4 = 10,240
static const size_t B_FSM   = 11810560;     // 5*2*256*1024*2 = 5,242,880 (bf16)
static const size_t B_MU    = 17053440;     // 5*256*4 = 5,120
static const size_t B_VAR   = 17058560;     // 5,120
static const size_t B_WC    = 17063680;     // 5*256*512*2 = 1,310,720
static const size_t B_BIAS2 = 18374400;     // 5,120
static const size_t B_UNION = 18379520;     // 40,304,640 union region
// phase 1: X_all_hi +0 (15,728,640), X_all_lo +15,728,640, wp_hi +31,457,280, wp_lo +35,880,960
// phase 2 (per level): fin_part +0 (20*2*256*1024*2 = 20,971,520) -> reduce20 -> fsm;
//                      then fin_big fp32 +0 (<=33,554,432) overwrites it
static const size_t U_XH    = 0;
static const size_t U_XL    = 15728640;
static const size_t U_WPH   = 31457280;
static const size_t U_WPL   = 35880960;
static const size_t U_FPART = 0;
static const size_t WS_BYTES = 58684160;    // ~58.7 MB

// ---------------- bf16 helpers (RNE) ----------------
__device__ inline unsigned short f2bf(float x) {
    unsigned u = __float_as_uint(x);
    return (unsigned short)((u + 0x7fffu + ((u >> 16) & 1u)) >> 16);
}
__device__ inline float bf2f(unsigned short u) {
    return __uint_as_float(((unsigned)u) << 16);
}
__device__ inline void bf16split(float x, unsigned short& hi, unsigned short& lo) {
    unsigned u = __float_as_uint(x);
    unsigned hb = (u + 0x7fffu + ((u >> 16) & 1u)) >> 16;
    hi = (unsigned short)hb;
    float hf = __uint_as_float(hb << 16);
    float r = x - hf;
    unsigned ur = __float_as_uint(r);
    lo = (unsigned short)((ur + 0x7fffu + ((ur >> 16) & 1u)) >> 16);
}
__device__ inline const float* sel5(const float* a, const float* b, const float* c,
                                    const float* d, const float* e, int i) {
    return i == 0 ? a : i == 1 ? b : i == 2 ? c : i == 3 ? d : e;
}

// ---------------- weight pre-transform ----------------
__global__ __launch_bounds__(256) void prep_weights(
    const float* __restrict__ kt_w, const float* __restrict__ kt_b,
    const float* __restrict__ vt_w, const float* __restrict__ vt_b,
    const float* __restrict__ kq_w, const float* __restrict__ kq_b,
    const float* __restrict__ vq_w, const float* __restrict__ vq_b,
    short* __restrict__ wp_hi, short* __restrict__ wp_lo, float* __restrict__ biasc)
{
    const int oc = blockIdx.x;    // 0..159
    const int s  = blockIdx.y;    // 0..5 (0 = stage A, 1+idx = level)
    const int ic = threadIdx.x;   // 0..255
    const bool iskey = oc < 32;
    const int ocl = iskey ? oc : oc - 32;
    const float scale = (iskey && s > 0) ? 1.4426950408889634f : 1.0f;
    const float* w = iskey
        ? (s == 0 ? kt_w : kq_w + (size_t)(s - 1) * 32 * 256 * 9)
        : (s == 0 ? vt_w : vq_w + (size_t)(s - 1) * 128 * 256 * 9);
    const float* wsrc = w + ((size_t)ocl * 256 + ic) * 9;
#pragma unroll
    for (int t = 0; t < 9; ++t) {
        unsigned short h, l; bf16split(wsrc[t] * scale, h, l);
        size_t d = ((size_t)(s * 9 + t) * 160 + oc) * 256 + ic;
        wp_hi[d] = (short)h; wp_lo[d] = (short)l;
    }
    if (ic == 0) {
        const float* bptr = iskey
            ? (s == 0 ? kt_b : kq_b + (s - 1) * 32)
            : (s == 0 ? vt_b : vq_b + (s - 1) * 128);
        biasc[s * 160 + oc] = bptr[ocl] * scale;
    }
}

// ---------------- fp32 [20][256][1024] -> bf16 hi/lo X_all imgs 0..19 ----------------
__global__ __launch_bounds__(256) void transpose_split(
    const float* __restrict__ in,
    unsigned short* __restrict__ oh, unsigned short* __restrict__ ol)
{
    __shared__ float s[16][260];
    const int n = blockIdx.x, ch = blockIdx.y, p0 = blockIdx.z * 256;
    const int tid = threadIdx.x;
#pragma unroll
    for (int i = 0; i < 16; ++i)
        s[i][tid] = in[((size_t)(n * 256 + ch * 16 + i)) * 1024 + p0 + tid];
    __syncthreads();
    union { unsigned short u[16]; bf16x8 v[2]; } h8, l8;
#pragma unroll
    for (int i = 0; i < 16; ++i) bf16split(s[i][tid], h8.u[i], l8.u[i]);
    size_t base = ((size_t)(n * 16 + ch) * 1024 + p0 + tid) * 16;
    *(bf16x8*)&oh[base] = h8.v[0]; *(bf16x8*)&oh[base + 8] = h8.v[1];
    *(bf16x8*)&ol[base] = l8.v[0]; *(bf16x8*)&ol[base + 8] = l8.v[1];
}

// ---------------- batched per (lvl,b,c) spatial mean ----------------
__global__ __launch_bounds__(256) void mean2d_all(
    const float* f0, const float* f1, const float* f2, const float* f3, const float* f4,
    float* __restrict__ mean)
{
    const int lvl = blockIdx.y;
    const float* f = sel5(f0, f1, f2, f3, f4, lvl);
    const int H = 128 >> lvl, HW = H * H;
    const int bc = blockIdx.x;
    const float* src = f + (size_t)bc * HW;
    float s = 0.f;
    for (int i = threadIdx.x; i < HW; i += 256) s += src[i];
#pragma unroll
    for (int off = 32; off; off >>= 1) s += __shfl_xor(s, off);
    __shared__ float red[4];
    if ((threadIdx.x & 63) == 0) red[threadIdx.x >> 6] = s;
    __syncthreads();
    if (threadIdx.x == 0)
        mean[lvl * 512 + bc] = (red[0] + red[1] + red[2] + red[3]) / (float)HW;
}

// ---------------- batched resize (HxH->32x32) + mean-sub -> X_all imgs 20..29 ----------------
__global__ __launch_bounds__(256) void resizeT_all(
    const float* f0, const float* f1, const float* f2, const float* f3, const float* f4,
    const float* __restrict__ mean,
    unsigned short* __restrict__ oh, unsigned short* __restrict__ ol)
{
    __shared__ float s[16][260];
    const int lvl = blockIdx.z >> 2;
    const int p0 = (blockIdx.z & 3) * 256;
    const int b = blockIdx.x, ch = blockIdx.y;
    const float* f = sel5(f0, f1, f2, f3, f4, lvl);
    const int H = 128 >> lvl;
    const int img = 20 + lvl * 2 + b;
    const int tid = threadIdx.x;
    const int p = p0 + tid, y = p >> 5, x = p & 31;
    float fy = (float)y * (float)(H - 1) / 31.0f;
    float fx = (float)x * (float)(H - 1) / 31.0f;
    int y0 = (int)fy; int y1 = min(y0 + 1, H - 1); float wy = fy - (float)y0;
    int x0 = (int)fx; int x1 = min(x0 + 1, H - 1); float wx = fx - (float)x0;
#pragma unroll
    for (int i = 0; i < 16; ++i) {
        int c = ch * 16 + i;
        const float* pf = f + ((size_t)(b * 256 + c)) * H * H;
        float a = pf[y0 * H + x0], bb = pf[y1 * H + x0];
        float cc = pf[y0 * H + x1], d = pf[y1 * H + x1];
        float c0 = a + (bb - a) * wy;
        float c1 = cc + (d - cc) * wy;
        s[i][tid] = c0 + (c1 - c0) * wx - mean[lvl * 512 + b * 256 + c];
    }
    __syncthreads();
    union { unsigned short u[16]; bf16x8 v[2]; } h8, l8;
#pragma unroll
    for (int i = 0; i < 16; ++i) bf16split(s[i][tid], h8.u[i], l8.u[i]);
    size_t base = ((size_t)(img * 16 + ch) * 1024 + p) * 16;
    *(bf16x8*)&oh[base] = h8.v[0]; *(bf16x8*)&oh[base + 8] = h8.v[1];
    *(bf16x8*)&ol[base] = l8.v[0]; *(bf16x8*)&ol[base + 8] = l8.v[1];
}

// ---------------- merged direct MFMA 3x3 conv: ic split across waves + LDS reduce ----------------
// grid (30 img, 16 rowpair, 5 grp); block 256 = 4 waves, wave w does ic chunks 4w..4w+3
__global__ __launch_bounds__(256) void conv3x3_all(
    const unsigned short* __restrict__ xT_h,  // [30][16][1024][16]
    const unsigned short* __restrict__ xT_l,
    const short* __restrict__ wp_hi_all,      // [6][9][160][256]
    const short* __restrict__ wp_lo_all,
    const float* __restrict__ biasc_all,      // [6][160]
    unsigned short* __restrict__ kt_hi, unsigned short* __restrict__ kt_lo, // [20][1024][32]
    unsigned short* __restrict__ vt,                                         // [20][128][1024]
    unsigned short* __restrict__ kq_hi, unsigned short* __restrict__ kq_lo, // [10][1024][32]
    unsigned short* __restrict__ vq)                                         // [10][128][1024]
{
    __shared__ float s_red[4][2][16][64];     // 32 KB
    const int tid = threadIdx.x;
    const int img = blockIdx.x;
    const int yp  = blockIdx.y;
    const int grp = blockIdx.z;
    const bool iskey = (grp == 0);
    const int set = (img < 20) ? 0 : 1 + ((img - 20) >> 1);
    const int ocb = grp * 32;
    const int wave = tid >> 6, lane = tid & 63, l31 = tid & 31, lh = (tid >> 5) & 1;
    const int y0 = yp * 2;

    f32x16 acc0 = {}, acc1 = {};
    const bf16x8 bz = {};
    const unsigned short* xh = xT_h + (size_t)img * 16 * 16384;
    const unsigned short* xl = xT_l + (size_t)img * 16 * 16384;
    const short* wph = wp_hi_all + (size_t)set * 368640;
    const short* wpl = wp_lo_all + (size_t)set * 368640;
    const float* bset = biasc_all + set * 160;

    for (int cc = 0; cc < 4; ++cc) {
        const int ch = (wave << 2) + cc;
        const unsigned short* xhc = xh + (size_t)ch * 16384 + lh * 8;
        const unsigned short* xlc = xl + (size_t)ch * 16384 + lh * 8;
#pragma unroll
        for (int tg = 0; tg < 3; ++tg) {
            bf16x8 wh[3], wl[3];
#pragma unroll
            for (int tl = 0; tl < 3; ++tl) {
                size_t wi = ((size_t)((tg * 3 + tl) * 160 + ocb + l31)) * 256 + (ch << 4) + lh * 8;
                wh[tl] = *(const bf16x8*)&wph[wi];
                if (iskey) wl[tl] = *(const bf16x8*)&wpl[wi];
            }
#pragma unroll
            for (int nt = 0; nt < 2; ++nt) {
                const int ri = y0 + nt - 1 + tg;
                const bool rok = (ri >= 0 && ri < 32);
#pragma unroll
                for (int tl = 0; tl < 3; ++tl) {
                    const int x = l31 + tl - 1;
                    const bool ok = rok && (x >= 0) && (x < 32);
                    bf16x8 bh = bz, bl = bz;
                    if (ok) {
                        const int p = ri * 32 + x;
                        bh = *(const bf16x8*)&xhc[p * 16];
                        if (iskey) bl = *(const bf16x8*)&xlc[p * 16];
                    }
                    f32x16& a = nt ? acc1 : acc0;
                    a = __builtin_amdgcn_mfma_f32_32x32x16_bf16(wh[tl], bh, a, 0, 0, 0);
                    if (iskey) {
                        a = __builtin_amdgcn_mfma_f32_32x32x16_bf16(wh[tl], bl, a, 0, 0, 0);
                        a = __builtin_amdgcn_mfma_f32_32x32x16_bf16(wl[tl], bh, a, 0, 0, 0);
                    }
                }
            }
        }
    }
    // cross-wave ic reduce through LDS
#pragma unroll
    for (int r = 0; r < 16; ++r) {
        s_red[wave][0][r][lane] = acc0[r];
        s_red[wave][1][r][lane] = acc1[r];
    }
    __syncthreads();
    float r0[4], r1[4];
#pragma unroll
    for (int j = 0; j < 4; ++j) {
        int r = (wave << 2) + j;
        r0[j] = s_red[0][0][r][lane] + s_red[1][0][r][lane] + s_red[2][0][r][lane] + s_red[3][0][r][lane];
        r1[j] = s_red[0][1][r][lane] + s_red[1][1][r][lane] + s_red[2][1][r][lane] + s_red[3][1][r][lane];
    }
    // epilogue: wave w owns the r-quad qd = w (reg r = 4*w + j -> row j + 8*w + 4*lh)
    if (iskey) {
#pragma unroll
        for (int nt = 0; nt < 2; ++nt) {
            const float* rr = nt ? r1 : r0;
            int p = (y0 + nt) * 32 + l31;
            int ocq = 8 * wave + 4 * lh;
            us4 h4, l4;
#pragma unroll
            for (int j = 0; j < 4; ++j) {
                unsigned short h, l;
                bf16split(rr[j] + bset[ocq + j], h, l);
                h4[j] = h; l4[j] = l;
            }
            if (img < 20) {
                size_t base = ((size_t)img * 1024 + p) * 32;
                *(us4*)&kt_hi[base + ocq] = h4;
                *(us4*)&kt_lo[base + ocq] = l4;
            } else {
                size_t base = ((size_t)(img - 20) * 1024 + p) * 32;
                *(us4*)&kq_hi[base + ocq] = h4;
                *(us4*)&kq_lo[base + ocq] = l4;
            }
        }
    } else {
#pragma unroll
        for (int nt = 0; nt < 2; ++nt) {
            const float* rr = nt ? r1 : r0;
            int p = (y0 + nt) * 32 + l31;
#pragma unroll
            for (int j = 0; j < 4; ++j) {
                int pat = j + 8 * wave + 4 * lh;
                int vo = (ocb - 32) + pat;
                unsigned short val = f2bf(rr[j] + bset[32 + vo]);
                if (img < 20) vt[((size_t)img * 128 + vo) * 1024 + p] = val;
                else          vq[((size_t)(img - 20) * 128 + vo) * 1024 + p] = val;
            }
        }
    }
}

// ---------------- flash relation-attention (double-buffered s_v, 1 barrier/step) ----------------
// grid (16 t-tiles of 64, 2 b, 20 n), block 256 = 4 waves: tw = w&1, vw = w>>1
__global__ __launch_bounds__(256, 3) void flash2(
    const unsigned short* __restrict__ kt_hi, const unsigned short* __restrict__ kt_lo,
    const unsigned short* __restrict__ vt_bf,
    const unsigned short* __restrict__ kq_hi, const unsigned short* __restrict__ kq_lo,
    const unsigned short* __restrict__ vq_bf,
    unsigned short* __restrict__ fin_part)   // [20][2][256][1024] bf16
{
    __shared__ unsigned short s_v[2][256 * 40];   // 40 KB double buffer
    const int tid = threadIdx.x;
    const int t0 = blockIdx.x * 64;
    const int b  = blockIdx.y;
    const int n  = blockIdx.z;
    const int wave = tid >> 6, lane = tid & 63, l31 = lane & 31, lh = lane >> 5;
    const int tw = wave & 1, vw = wave >> 1;

    const int trow = t0 + tw * 32 + l31;
    bf16x8 btk_h0, btk_h1, btk_l0, btk_l1;
    {
        size_t g = ((size_t)n * 1024 + trow) * 32 + lh * 8;
        btk_h0 = *(const bf16x8*)&kt_hi[g];
        btk_h1 = *(const bf16x8*)&kt_hi[g + 16];
        btk_l0 = *(const bf16x8*)&kt_lo[g];
        btk_l1 = *(const bf16x8*)&kt_lo[g + 16];
    }

    const unsigned short* vsrc = (tid < 128)
        ? &vq_bf[((size_t)b * 128 + tid) * 1024]
        : &vt_bf[((size_t)n * 128 + (tid - 128)) * 1024];
    const unsigned short* kqh = kq_hi + (size_t)b * 1024 * 32;
    const unsigned short* kql = kq_lo + (size_t)b * 1024 * 32;

    bf16x8 nv0 = *(const bf16x8*)&vsrc[0];
    bf16x8 nv1 = *(const bf16x8*)&vsrc[8];
    bf16x8 nv2 = *(const bf16x8*)&vsrc[16];
    bf16x8 nv3 = *(const bf16x8*)&vsrc[24];
    bf16x8 nah0 = *(const bf16x8*)&kqh[(size_t)l31 * 32 + lh * 8];
    bf16x8 nah1 = *(const bf16x8*)&kqh[(size_t)l31 * 32 + 16 + lh * 8];
    bf16x8 nal0 = *(const bf16x8*)&kql[(size_t)l31 * 32 + lh * 8];
    bf16x8 nal1 = *(const bf16x8*)&kql[(size_t)l31 * 32 + 16 + lh * 8];

    f32x16 acc0 = {}, acc1 = {}, acc2 = {}, acc3 = {};
    float m = -3.0e38f, lsum = 0.f;

    for (int q0 = 0; q0 < 1024; q0 += 32) {
        const int c = (q0 >> 5) & 1;
        // write current step's V into buffer c.
        // Safety vs step k-2's reads of buffer c: separated by step k-1's barrier
        // (program order: reads(c) at k-2 -> write(c^1) at k-1 -> barrier -> write(c) at k).
        {
            unsigned short* dst = &s_v[c][tid * 40];
            *(bf16x8*)&dst[0]  = nv0;
            *(bf16x8*)&dst[8]  = nv1;
            *(bf16x8*)&dst[16] = nv2;
            *(bf16x8*)&dst[24] = nv3;
        }
        bf16x8 ah0 = nah0, ah1 = nah1, al0 = nal0, al1 = nal1;

        if (q0 + 32 < 1024) {   // prefetch next step (overlaps with compute below)
            const int qn = q0 + 32;
            nv0 = *(const bf16x8*)&vsrc[qn];
            nv1 = *(const bf16x8*)&vsrc[qn + 8];
            nv2 = *(const bf16x8*)&vsrc[qn + 16];
            nv3 = *(const bf16x8*)&vsrc[qn + 24];
            size_t kb = (size_t)(qn + l31) * 32 + lh * 8;
            nah0 = *(const bf16x8*)&kqh[kb];
            nah1 = *(const bf16x8*)&kqh[kb + 16];
            nal0 = *(const bf16x8*)&kql[kb];
            nal1 = *(const bf16x8*)&kql[kb + 16];
        }
        __syncthreads();   // s_v[c] visible to all waves

        // S tile [32 q][32 t] in log2 domain (kq pre-scaled by log2 e)
        f32x16 s = {};
        s = __builtin_amdgcn_mfma_f32_32x32x16_bf16(ah0, btk_h0, s, 0, 0, 0);
        s = __builtin_amdgcn_mfma_f32_32x32x16_bf16(ah0, btk_l0, s, 0, 0, 0);
        s = __builtin_amdgcn_mfma_f32_32x32x16_bf16(al0, btk_h0, s, 0, 0, 0);
        s = __builtin_amdgcn_mfma_f32_32x32x16_bf16(ah1, btk_h1, s, 0, 0, 0);
        s = __builtin_amdgcn_mfma_f32_32x32x16_bf16(ah1, btk_l1, s, 0, 0, 0);
        s = __builtin_amdgcn_mfma_f32_32x32x16_bf16(al1, btk_h1, s, 0, 0, 0);

        float pmax = s[0];
#pragma unroll
        for (int r = 1; r < 16; ++r) pmax = fmaxf(pmax, s[r]);
        pmax = fmaxf(pmax, __shfl_xor(pmax, 32));
        if (!__all(pmax <= m + 11.5417f)) {
            float mnew = fmaxf(m, pmax);
            float sc = __builtin_amdgcn_exp2f(m - mnew);
            m = mnew; lsum *= sc;
            acc0 *= sc; acc1 *= sc; acc2 *= sc; acc3 *= sc;
        }
        float pv[16]; float ps = 0.f;
#pragma unroll
        for (int r = 0; r < 16; ++r) { pv[r] = __builtin_amdgcn_exp2f(s[r] - m); ps += pv[r]; }
        lsum += ps;

        unsigned a0, a1, a2, a3, c0, c1, c2, c3;
        asm("v_cvt_pk_bf16_f32 %0, %1, %2" : "=v"(a0) : "v"(pv[0]),  "v"(pv[1]));
        asm("v_cvt_pk_bf16_f32 %0, %1, %2" : "=v"(a1) : "v"(pv[2]),  "v"(pv[3]));
        asm("v_cvt_pk_bf16_f32 %0, %1, %2" : "=v"(a2) : "v"(pv[4]),  "v"(pv[5]));
        asm("v_cvt_pk_bf16_f32 %0, %1, %2" : "=v"(a3) : "v"(pv[6]),  "v"(pv[7]));
        asm("v_cvt_pk_bf16_f32 %0, %1, %2" : "=v"(c0) : "v"(pv[8]),  "v"(pv[9]));
        asm("v_cvt_pk_bf16_f32 %0, %1, %2" : "=v"(c1) : "v"(pv[10]), "v"(pv[11]));
        asm("v_cvt_pk_bf16_f32 %0, %1, %2" : "=v"(c2) : "v"(pv[12]), "v"(pv[13]));
        asm("v_cvt_pk_bf16_f32 %0, %1, %2" : "=v"(c3) : "v"(pv[14]), "v"(pv[15]));
        asm("v_permlane32_swap_b32 %0, %1" : "+v"(a0), "+v"(a2));
        asm("v_permlane32_swap_b32 %0, %1" : "+v"(a1), "+v"(a3));
        asm("v_permlane32_swap_b32 %0, %1" : "+v"(c0), "+v"(c2));
        asm("v_permlane32_swap_b32 %0, %1" : "+v"(c1), "+v"(c3));
        union { unsigned u[4]; bf16x8 v; } f0, f1;
        f0.u[0] = a0; f0.u[1] = a1; f0.u[2] = a2; f0.u[3] = a3;
        f1.u[0] = c0; f1.u[1] = c1; f1.u[2] = c2; f1.u[3] = c3;

#pragma unroll
        for (int vs = 0; vs < 4; ++vs) {
            const unsigned short* vr = &s_v[c][(vw * 128 + vs * 32 + l31) * 40 + lh * 8];
            bf16x8 va0 = *(const bf16x8*)&vr[0];
            bf16x8 va1 = *(const bf16x8*)&vr[16];
            f32x16& a = (vs == 0) ? acc0 : (vs == 1) ? acc1 : (vs == 2) ? acc2 : acc3;
            a = __builtin_amdgcn_mfma_f32_32x32x16_bf16(va0, f0.v, a, 0, 0, 0);
            a = __builtin_amdgcn_mfma_f32_32x32x16_bf16(va1, f1.v, a, 0, 0, 0);
        }
    }

    float lt = lsum + __shfl_xor(lsum, 32);
    float linv = 1.f / lt;
    unsigned short* outp = fin_part + ((size_t)(n * 2 + b)) * 256 * 1024;
    const int tg = t0 + tw * 32 + l31;
#pragma unroll
    for (int vs = 0; vs < 4; ++vs) {
        const f32x16& a = (vs == 0) ? acc0 : (vs == 1) ? acc1 : (vs == 2) ? acc2 : acc3;
#pragma unroll
        for (int r = 0; r < 16; ++r) {
            int v = vw * 128 + vs * 32 + (r & 3) + 8 * (r >> 2) + 4 * lh;
            outp[(size_t)v * 1024 + tg] = f2bf(a[r] * linv);
        }
    }
}

// ---------------- sum 20 bf16 n-slabs -> bf16 fsm slice ----------------
__global__ __launch_bounds__(256) void reduce20_bf(
    const unsigned short* __restrict__ part, unsigned short* __restrict__ out)
{
    size_t i = (size_t)blockIdx.x * 256 + threadIdx.x;
    float s = 0.f;
#pragma unroll
    for (int nn = 0; nn < 20; ++nn) s += bf2f(part[(size_t)nn * 524288 + i]);
    out[i] = f2bf(s);
}

// ---------------- bilinear upsample 32x32 -> HxH, bf16 in / fp32 out ----------------
__global__ __launch_bounds__(256) void upsample_bf(
    const unsigned short* __restrict__ in,   // level slice [2][256][1024] bf16
    float* __restrict__ out,                 // [2][256][H][H] fp32
    int oh, int ow, int total)
{
    int idx = blockIdx.x * 256 + threadIdx.x;
    if (idx >= total) return;
    int x  = idx % ow;
    int y  = (idx / ow) % oh;
    int bc = idx / (ow * oh);
    float fy = (float)y * 31.0f / (float)(oh - 1);
    float fx = (float)x * 31.0f / (float)(ow - 1);
    int y0 = (int)fy; int y1 = min(y0 + 1, 31); float wy = fy - (float)y0;
    int x0 = (int)fx; int x1 = min(x0 + 1, 31); float wx = fx - (float)x0;
    const unsigned short* p = in + (size_t)bc * 1024;
    float a = bf2f(p[y0 * 32 + x0]), b = bf2f(p[y1 * 32 + x0]);
    float c = bf2f(p[y0 * 32 + x1]), d = bf2f(p[y1 * 32 + x1]);
    float c0 = a + (b - a) * wy;
    float c1 = c + (d - c) * wy;
    out[idx] = c0 + (c1 - c0) * wx;
}

// ---------------- BN stats over (b, spatial) per channel ----------------
__global__ __launch_bounds__(256) void bnstats_kernel(
    const float* __restrict__ fin, float* __restrict__ mu, float* __restrict__ var, int HW)
{
    const int c = blockIdx.x;
    float s = 0.f, s2 = 0.f;
    for (int b = 0; b < 2; ++b) {
        const float* p = fin + ((size_t)b * 256 + c) * HW;
        for (int i = threadIdx.x; i < HW; i += 256) {
            float v = p[i]; s += v; s2 += v * v;
        }
    }
#pragma unroll
    for (int off = 32; off; off >>= 1) {
        s  += __shfl_xor(s, off);
        s2 += __shfl_xor(s2, off);
    }
    __shared__ float r1[4], r2[4];
    if ((threadIdx.x & 63) == 0) { r1[threadIdx.x >> 6] = s; r2[threadIdx.x >> 6] = s2; }
    __syncthreads();
    if (threadIdx.x == 0) {
        float cnt = 2.f * (float)HW;
        float mm = (r1[0] + r1[1] + r1[2] + r1[3]) / cnt;
        float qq = (r2[0] + r2[1] + r2[2] + r2[3]) / cnt;
        mu[c] = mm; var[c] = qq - mm * mm;
    }
}

// ---------------- fold BN into comb weights ----------------
__global__ __launch_bounds__(256) void prep_comb(
    const float* __restrict__ comb_w, const float* __restrict__ comb_b,
    const float* __restrict__ gamma, const float* __restrict__ beta,
    const float* __restrict__ mu, const float* __restrict__ var,
    short* __restrict__ wc, float* __restrict__ bias2)
{
    const int oc = blockIdx.x;
    const int ic = threadIdx.x;
    float a  = gamma[ic] * rsqrtf(var[ic] + 1e-5f);
    float bb = beta[ic] - mu[ic] * a;
    float w1 = comb_w[(size_t)oc * 512 + ic];
    float w2 = comb_w[(size_t)oc * 512 + 256 + ic];
    wc[(size_t)oc * 512 + ic]       = (short)f2bf(w1);
    wc[(size_t)oc * 512 + 256 + ic] = (short)f2bf(w2 * a);
    float s = w2 * bb;
#pragma unroll
    for (int off = 32; off; off >>= 1) s += __shfl_xor(s, off);
    __shared__ float red[4];
    if ((threadIdx.x & 63) == 0) red[threadIdx.x >> 6] = s;
    __syncthreads();
    if (threadIdx.x == 0)
        bias2[oc] = comb_b[oc] + red[0] + red[1] + red[2] + red[3];
}

// ---------------- comb 1x1 conv as MFMA GEMM (fp32 fin) ----------------
__global__ __launch_bounds__(256, 1) void comb_mfma(
    const float* __restrict__ f,    // [2][256][HW]
    const float* __restrict__ fin,  // [2][256][HW] fp32
    const short* __restrict__ wc,   // [256][512] bf16
    const float* __restrict__ bias2,
    float* __restrict__ out, int HW)
{
    __shared__ short s_wc[256 * 40];
    __shared__ short s_xc[128 * 40];
    const int tid = threadIdx.x;
    const int p0 = blockIdx.x * 128;
    const int b  = blockIdx.y;
    const int wv = tid >> 6, l31 = tid & 31, lh = (tid >> 5) & 1;
    const int wm = wv >> 1, wn = wv & 1;

    f32x16 acc[4][2];
#pragma unroll
    for (int i = 0; i < 4; ++i)
#pragma unroll
        for (int j = 0; j < 2; ++j)
#pragma unroll
            for (int r = 0; r < 16; ++r) acc[i][j][r] = 0.f;

    for (int k0 = 0; k0 < 512; k0 += 32) {
        __syncthreads();
        for (int u = tid; u < 512; u += 256) {
            int r = u >> 1, h = u & 1;
            *(bf16x8*)&s_wc[r * 40 + h * 16 + 0] = *(const bf16x8*)&wc[(size_t)r * 512 + k0 + h * 16];
            *(bf16x8*)&s_wc[r * 40 + h * 16 + 8] = *(const bf16x8*)&wc[(size_t)r * 512 + k0 + h * 16 + 8];
        }
        for (int u = tid; u < 1024; u += 256) {
            int kr = u >> 5, n4 = (u & 31) * 4;
            int ck = k0 + kr;
            const float* bsrc = (ck < 256)
                ? f   + ((size_t)(b * 256 + ck)) * HW
                : fin + ((size_t)(b * 256 + ck - 256)) * HW;
            int p = p0 + n4;
            float v0, v1, v2, v3;
            if (p + 3 < HW) {
                float4 v4 = *(const float4*)&bsrc[p];
                v0 = v4.x; v1 = v4.y; v2 = v4.z; v3 = v4.w;
            } else {
                v0 = bsrc[min(p,     HW - 1)];
                v1 = bsrc[min(p + 1, HW - 1)];
                v2 = bsrc[min(p + 2, HW - 1)];
                v3 = bsrc[min(p + 3, HW - 1)];
            }
            s_xc[(n4 + 0) * 40 + kr] = (short)f2bf(v0);
            s_xc[(n4 + 1) * 40 + kr] = (short)f2bf(v1);
            s_xc[(n4 + 2) * 40 + kr] = (short)f2bf(v2);
            s_xc[(n4 + 3) * 40 + kr] = (short)f2bf(v3);
        }
        __syncthreads();
#pragma unroll
        for (int ks = 0; ks < 2; ++ks) {
            bf16x8 a[4], bx[2];
#pragma unroll
            for (int mi = 0; mi < 4; ++mi)
                a[mi] = *(const bf16x8*)&s_wc[(wm * 128 + mi * 32 + l31) * 40 + ks * 16 + lh * 8];
#pragma unroll
            for (int ni = 0; ni < 2; ++ni)
                bx[ni] = *(const bf16x8*)&s_xc[(wn * 64 + ni * 32 + l31) * 40 + ks * 16 + lh * 8];
#pragma unroll
            for (int mi = 0; mi < 4; ++mi)
#pragma unroll
                for (int ni = 0; ni < 2; ++ni)
                    acc[mi][ni] = __builtin_amdgcn_mfma_f32_32x32x16_bf16(a[mi], bx[ni], acc[mi][ni], 0, 0, 0);
        }
    }
#pragma unroll
    for (int mi = 0; mi < 4; ++mi) {
#pragma unroll
        for (int ni = 0; ni < 2; ++ni) {
            int p = p0 + wn * 64 + ni * 32 + l31;
            if (p < HW) {
#pragma unroll
                for (int r = 0; r < 16; ++r) {
                    int oc = wm * 128 + mi * 32 + (r & 3) + 8 * (r >> 2) + 4 * lh;
                    out[((size_t)(b * 256 + oc)) * HW + p] = acc[mi][ni][r] + bias2[oc];
                }
            }
        }
    }
}

// ---------------- host orchestration ----------------
extern "C" void kernel_launch(void* const* d_in, const int* in_sizes, int n_in,
                              void* d_out, int out_size, void* d_ws, size_t ws_size,
                              hipStream_t stream) {
    if (ws_size < WS_BYTES) return;

    const float* feats[5];
    for (int i = 0; i < 5; ++i) feats[i] = (const float*)d_in[i];
    const float* attn     = (const float*)d_in[5];
    const float* key_t_w  = (const float*)d_in[6];
    const float* key_t_b  = (const float*)d_in[7];
    const float* val_t_w  = (const float*)d_in[8];
    const float* val_t_b  = (const float*)d_in[9];
    const float* key_q_w  = (const float*)d_in[10];
    const float* key_q_b  = (const float*)d_in[11];
    const float* val_q_w  = (const float*)d_in[12];
    const float* val_q_b  = (const float*)d_in[13];
    const float* bn_gamma = (const float*)d_in[14];
    const float* bn_beta  = (const float*)d_in[15];
    const float* comb_w   = (const float*)d_in[16];
    const float* comb_b   = (const float*)d_in[17];

    char* ws = (char*)d_ws;
    float* biasc = (float*)(ws + B_BIASC);
    unsigned short* kt_hi = (unsigned short*)(ws + B_KTH);
    unsigned short* kt_lo = (unsigned short*)(ws + B_KTL);
    unsigned short* vt    = (unsigned short*)(ws + B_VT);
    unsigned short* kq_hi = (unsigned short*)(ws + B_KQH);
    unsigned short* kq_lo = (unsigned short*)(ws + B_KQL);
    unsigned short* vq    = (unsigned short*)(ws + B_VQ);
    float* mean_f = (float*)(ws + B_MEAN);
    unsigned short* fsm = (unsigned short*)(ws + B_FSM);
    float* mu     = (float*)(ws + B_MU);
    float* var    = (float*)(ws + B_VAR);
    short* wc_bf  = (short*)(ws + B_WC);
    float* bias2  = (float*)(ws + B_BIAS2);
    unsigned short* X_h = (unsigned short*)(ws + B_UNION + U_XH);
    unsigned short* X_l = (unsigned short*)(ws + B_UNION + U_XL);
    short* wp_hi = (short*)(ws + B_UNION + U_WPH);
    short* wp_lo = (short*)(ws + B_UNION + U_WPL);
    unsigned short* fin_part = (unsigned short*)(ws + B_UNION + U_FPART);
    float* fin_big = (float*)(ws + B_UNION);   // overwrites fin_part after reduce20

    prep_weights<<<dim3(160, 6), 256, 0, stream>>>(
        key_t_w, key_t_b, val_t_w, val_t_b, key_q_w, key_q_b, val_q_w, val_q_b,
        wp_hi, wp_lo, biasc);

    transpose_split<<<dim3(20, 16, 4), 256, 0, stream>>>(attn, X_h, X_l);

    mean2d_all<<<dim3(512, 5), 256, 0, stream>>>(
        feats[0], feats[1], feats[2], feats[3], feats[4], mean_f);

    resizeT_all<<<dim3(2, 16, 20), 256, 0, stream>>>(
        feats[0], feats[1], feats[2], feats[3], feats[4], mean_f, X_h, X_l);

    conv3x3_all<<<dim3(30, 16, 5), 256, 0, stream>>>(
        X_h, X_l, wp_hi, wp_lo, biasc, kt_hi, kt_lo, vt, kq_hi, kq_lo, vq);

    size_t out_off = 0;
    for (int idx = 0; idx < 5; ++idx) {
        const int H = 128 >> idx, HW = H * H;
        const int total = 2 * 256 * HW;

        flash2<<<dim3(16, 2, 20), 256, 0, stream>>>(
            kt_hi, kt_lo, vt,
            kq_hi + (size_t)idx * 2 * 32768,
            kq_lo + (size_t)idx * 2 * 32768,
            vq + (size_t)idx * 2 * 131072,
            fin_part);

        reduce20_bf<<<2048, 256, 0, stream>>>(fin_part, fsm + (size_t)idx * 524288);

        upsample_bf<<<(total + 255) / 256, 256, 0, stream>>>(
            fsm + (size_t)idx * 524288, fin_big, H, H, total);

        bnstats_kernel<<<256, 256, 0, stream>>>(fin_big, mu + idx * 256, var + idx * 256, HW);

        prep_comb<<<256, 256, 0, stream>>>(
            comb_w, comb_b, bn_gamma + idx * 256, bn_beta + idx * 256,
            mu + idx * 256, var + idx * 256, wc_bf + (size_t)idx * 131072, bias2 + idx * 256);

        comb_mfma<<<dim3((HW + 127) / 128, 2), 256, 0, stream>>>(
            feats[idx], fin_big, wc_bf + (size_t)idx * 131072, bias2 + idx * 256,
            (float*)d_out + out_off, HW);

        out_off += (size_t)2 * 256 * HW;
    }
}